// Round 3
// baseline (10643.960 us; speedup 1.0000x reference)
//
// KalmanNetNN persistent kernel, MI355X (gfx950).
// R11: hide the redundant-l1 L2 stream inside the exchange flight windows.
//   Algebra: inn(t+1) = inn0(t+1) - CmA @ Delta(t), with
//     inn0(t+1) = y[t+1] - C@[A@xprior(t);1] known at iteration start,
//     Delta = 4-dim slot-reduce result. So l1a = W1a@inn0 (48/53 cols, 200KB
//     of the 266KB w1e stream) is computed in the wait windows:
//       C: waves 4-7 (rows 0..2080) while waves 0-3 poll h
//       D: waves 0-3 (rows 2080..2336) while waves 4-7 do l2
//       E: all waves (rows 2336..4160) + ghh while slot is in flight
//   Post-reduce tail per row (one 16B load: dx fp8 x4 | b1 fp8 | pad | W4 f16 x4):
//     l1 = ReLU(((l1a - W4.Delta)/||inn|| + wdx.Delta/||dx|| + b1)*INVWS)
//   W4 = (fp8-dequant W1a) @ (C[:, :4]@A) precomputed in build_w1e, packed into
//   the 8 pad bytes of each w1e row (no workspace growth).
//   Numerics: reassociation + f16-on-tiny-correction ~1e-6 rel, far below the
//   fp8 quantization already accepted.
// Also: revert R9/R10 gated poll to R8 full-packet poll (R10 showed +330us:
//   the settle round adds a dependent agent round trip; congestion theory dead).
//   Keep myh (register own-h, post-B barrier dropped).
// Predicted: step 16.2 -> ~14.3-15.4 us => 7.3-7.9 ms. VGPR ~128, FETCH flat.

#include <hip/hip_runtime.h>
#include <hip/hip_fp16.h>
#include <stdint.h>
#include <stddef.h>

typedef float v2f __attribute__((ext_vector_type(2)));

#define HID   2320
#define G3    6960
#define KIH   4160
#define KHH   2320
#define NBLK  232
#define NL2B  192              // blocks owning l2 rows (4 each = 768)
#define NTHR  512
#define UPB   10
#define TSEQ  512
#define KRES  1600
#define CH0   2080             // l1a rows done in C window (waves 4-7)
#define CH1   2336             // rows [CH0,CH1) in D window (waves 0-3)
#define INVWS (1.0f/128.0f)
#define SPINCAP (1u<<17)

// ---------------- workspace layout (bytes) ----------------
#define WS_WIH8 0L            // 6960*4160 fp8
#define WS_W1E  28953600L     // 4160*64 fp8 W1ext (48 inn w | 4 dx w | b1 | pad | W4 f16 x4)
#define WS_HBP  29219840L     // 2 x 232 x 128B h packets (10 tagged words)
#define WS_SLT  29279232L     // 2 x 232 x 64B slot packets (4 tagged words)
#define WS_END  29308928L

struct Offs {
  int l1s, hs, wih, whh, w2s, w3s, cs, as_, b3s, bih, bhh, b2s, gis, ghs,
      ts, inn, inn0, xq, cma, dxs, xpri, xpo, b4, nrm, l2r, slp;
  int total;
};

__host__ __device__ inline Offs mkoffs(int res) {
  Offs o; int p = 0;
#define ALLOC(name, bytes) { p = (p + 15) & ~15; o.name = p; p += (bytes); }
  ALLOC(l1s, KIH*4) ALLOC(hs, HID*4)
  ALLOC(wih, res ? 30*KRES : 16) ALLOC(whh, res ? 30*KHH : 16)
  ALLOC(w2s, res ? 4*HID : 16)
  ALLOC(w3s, 16*48*4) ALLOC(cs, 240*4) ALLOC(as_, 64) ALLOC(b3s, 192*4)
  ALLOC(bih, 120) ALLOC(bhh, 120) ALLOC(b2s, 16)
  ALLOC(gis, 120) ALLOC(ghs, 120)
  ALLOC(ts, 64) ALLOC(inn, 192) ALLOC(inn0, 192) ALLOC(xq, 16) ALLOC(cma, 768)
  ALLOC(dxs, 16) ALLOC(xpri, 16) ALLOC(xpo, 16) ALLOC(b4, 16) ALLOC(nrm, 16)
  ALLOC(l2r, 16) ALLOC(slp, 64)
#undef ALLOC
  o.total = (p + 63) & ~63;
  return o;
}

struct Params {
  const float *A, *C, *x0, *h0, *y, *W1, *b1, *Wih, *Whh, *bih, *bhh, *W2, *b2, *W3, *b3;
  const uint8_t *wih8, *w1e;
  uint64_t *hbp, *slt;
  float *out;
  int resident;
};

__device__ __forceinline__ uint8_t f2fp8(float v) {
  v = fminf(fmaxf(v * 128.f, -448.f), 448.f);
  int pk = __builtin_amdgcn_cvt_pk_fp8_f32(v, v, 0, false);
  return (uint8_t)(pk & 0xff);
}

// fire-and-forget tagged publish: one self-validating 8B word.
__device__ __forceinline__ void pub64(uint64_t* a, uint32_t tag, float v) {
  uint64_t w = ((uint64_t)tag << 32) | (uint64_t)__float_as_uint(v);
  __hip_atomic_store(a, w, __ATOMIC_RELAXED, __HIP_MEMORY_SCOPE_AGENT);
}

// full-packet poll (R8 form): all N tagged words each round, hot 8 rounds.
template<int N>
__device__ __forceinline__ void poll_pkt(const uint64_t* base, uint32_t want,
                                         float* out, bool& dead) {
  uint64_t v[N];
  uint32_t spins = 0;
  for (;;) {
    bool ok = true;
#pragma unroll
    for (int k = 0; k < N; ++k)
      v[k] = __hip_atomic_load(base + k, __ATOMIC_RELAXED, __HIP_MEMORY_SCOPE_AGENT);
#pragma unroll
    for (int k = 0; k < N; ++k) ok &= ((uint32_t)(v[k] >> 32) == want);
    if (ok || dead) break;
    ++spins;
    if (spins > 8) __builtin_amdgcn_s_sleep(2);
    if (spins > SPINCAP) dead = true;
  }
#pragma unroll
  for (int k = 0; k < N; ++k) out[k] = __uint_as_float((uint32_t)v[k]);
}

// 16-wide fp8 dot fragment: acc += dot(fp8x16(w), [a0 a1 a2 a3])
__device__ __forceinline__ float fma16(uint4 w, float4 a0, float4 a1,
                                       float4 a2, float4 a3, float acc) {
  v2f l0 = __builtin_amdgcn_cvt_pk_f32_fp8((int)w.x, false);
  v2f h0 = __builtin_amdgcn_cvt_pk_f32_fp8((int)w.x, true);
  v2f l1 = __builtin_amdgcn_cvt_pk_f32_fp8((int)w.y, false);
  v2f h1 = __builtin_amdgcn_cvt_pk_f32_fp8((int)w.y, true);
  v2f l2 = __builtin_amdgcn_cvt_pk_f32_fp8((int)w.z, false);
  v2f h2 = __builtin_amdgcn_cvt_pk_f32_fp8((int)w.z, true);
  v2f l3 = __builtin_amdgcn_cvt_pk_f32_fp8((int)w.w, false);
  v2f h3 = __builtin_amdgcn_cvt_pk_f32_fp8((int)w.w, true);
  acc = fmaf(l0.x,a0.x,acc); acc = fmaf(l0.y,a0.y,acc);
  acc = fmaf(h0.x,a0.z,acc); acc = fmaf(h0.y,a0.w,acc);
  acc = fmaf(l1.x,a1.x,acc); acc = fmaf(l1.y,a1.y,acc);
  acc = fmaf(h1.x,a1.z,acc); acc = fmaf(h1.y,a1.w,acc);
  acc = fmaf(l2.x,a2.x,acc); acc = fmaf(l2.y,a2.y,acc);
  acc = fmaf(h2.x,a2.z,acc); acc = fmaf(h2.y,a2.w,acc);
  acc = fmaf(l3.x,a3.x,acc); acc = fmaf(l3.y,a3.y,acc);
  acc = fmaf(h3.x,a3.z,acc); acc = fmaf(h3.y,a3.w,acc);
  return acc;
}

// fp8 row-dot, LDS weights, <=4 rows/wave, lanes split K.
__device__ __forceinline__ void dot8_lds(
    const float* __restrict__ acts, const uint8_t* __restrict__ w, int stride,
    int K, const int* lrows, int nr, int lane, float acc[4])
{
  int kb = 0;
  for (; kb + 256 <= K; kb += 256) {
    const float4 a = ((const float4*)(acts + kb))[lane];
#pragma unroll
    for (int j = 0; j < 4; ++j) if (j < nr) {
      uint32_t wb = *(const uint32_t*)(w + (size_t)lrows[j]*stride + kb + (lane<<2));
      v2f lo = __builtin_amdgcn_cvt_pk_f32_fp8((int)wb, false);
      v2f hi = __builtin_amdgcn_cvt_pk_f32_fp8((int)wb, true);
      acc[j] = fmaf(lo.x, a.x, acc[j]); acc[j] = fmaf(lo.y, a.y, acc[j]);
      acc[j] = fmaf(hi.x, a.z, acc[j]); acc[j] = fmaf(hi.y, a.w, acc[j]);
    }
  }
  int rem = K - kb;
  if ((lane << 2) < rem) {
    const float4 a = ((const float4*)(acts + kb))[lane];
#pragma unroll
    for (int j = 0; j < 4; ++j) if (j < nr) {
      uint32_t wb = *(const uint32_t*)(w + (size_t)lrows[j]*stride + kb + (lane<<2));
      v2f lo = __builtin_amdgcn_cvt_pk_f32_fp8((int)wb, false);
      v2f hi = __builtin_amdgcn_cvt_pk_f32_fp8((int)wb, true);
      acc[j] = fmaf(lo.x, a.x, acc[j]); acc[j] = fmaf(lo.y, a.y, acc[j]);
      acc[j] = fmaf(hi.x, a.z, acc[j]); acc[j] = fmaf(hi.y, a.w, acc[j]);
    }
  }
}

// fp8 row-dot, global weights, cols [K0,K).
__device__ __forceinline__ void dot8_glb(
    const float* __restrict__ acts, const uint8_t* __restrict__ gw, int gstride,
    int K0, int K, const int* grows, int nr, int lane, float acc[4])
{
  int kb = K0;
  for (; kb + 512 <= K; kb += 512) {
    const float4 a0 = ((const float4*)(acts + kb))[lane*2];
    const float4 a1 = ((const float4*)(acts + kb))[lane*2 + 1];
#pragma unroll
    for (int j = 0; j < 4; ++j) if (j < nr) {
      uint2 wb = *(const uint2*)(gw + (size_t)grows[j]*gstride + kb + (lane<<3));
      v2f l0 = __builtin_amdgcn_cvt_pk_f32_fp8((int)wb.x, false);
      v2f h0 = __builtin_amdgcn_cvt_pk_f32_fp8((int)wb.x, true);
      v2f l1 = __builtin_amdgcn_cvt_pk_f32_fp8((int)wb.y, false);
      v2f h1 = __builtin_amdgcn_cvt_pk_f32_fp8((int)wb.y, true);
      acc[j] = fmaf(l0.x, a0.x, acc[j]); acc[j] = fmaf(l0.y, a0.y, acc[j]);
      acc[j] = fmaf(h0.x, a0.z, acc[j]); acc[j] = fmaf(h0.y, a0.w, acc[j]);
      acc[j] = fmaf(l1.x, a1.x, acc[j]); acc[j] = fmaf(l1.y, a1.y, acc[j]);
      acc[j] = fmaf(h1.x, a1.z, acc[j]); acc[j] = fmaf(h1.y, a1.w, acc[j]);
    }
  }
  for (int e = kb + lane; e < K; e += 64) {
    float a = acts[e];
#pragma unroll
    for (int j = 0; j < 4; ++j) if (j < nr) {
      v2f lo = __builtin_amdgcn_cvt_pk_f32_fp8(
          (int)(uint32_t)gw[(size_t)grows[j]*gstride + e], false);
      acc[j] = fmaf(lo.x, a, acc[j]);
    }
  }
}

// f32 row-dot, global weights (fallback ghh).
__device__ __forceinline__ void dotf_glb(
    const float* __restrict__ acts, const float* __restrict__ gw, int gstride,
    int K, const int* grows, int nr, int lane, float acc[4])
{
  for (int k = lane; k < K; k += 64) {
    float a = acts[k];
#pragma unroll
    for (int j = 0; j < 4; ++j) if (j < nr)
      acc[j] = fmaf(gw[(size_t)grows[j]*gstride + k], a, acc[j]);
  }
}

extern "C" __global__ void __launch_bounds__(NTHR, 2) knet_main(Params p)
{
  extern __shared__ char smem[];
  const Offs o = mkoffs(p.resident);
  float*   L1S  = (float*)(smem + o.l1s);
  float*   HS   = (float*)(smem + o.hs);
  uint8_t* WIHR = (uint8_t*)(smem + o.wih);
  uint8_t* WHHR = (uint8_t*)(smem + o.whh);
  uint8_t* W2S  = (uint8_t*)(smem + o.w2s);
  float*   W3S  = (float*)(smem + o.w3s);
  float*   CS   = (float*)(smem + o.cs);
  float*   AS   = (float*)(smem + o.as_);
  float*   B3S  = (float*)(smem + o.b3s);
  float*   BIH  = (float*)(smem + o.bih);
  float*   BHH  = (float*)(smem + o.bhh);
  float*   B2S  = (float*)(smem + o.b2s);
  float*   GIS  = (float*)(smem + o.gis);
  float*   GHS  = (float*)(smem + o.ghs);
  float*   TS   = (float*)(smem + o.ts);
  float*   INNS = (float*)(smem + o.inn);
  float*   INN0 = (float*)(smem + o.inn0);
  float*   XQ   = (float*)(smem + o.xq);
  float*   CMA  = (float*)(smem + o.cma);
  float*   DXS  = (float*)(smem + o.dxs);
  float*   XPRI = (float*)(smem + o.xpri);
  float*   XPO  = (float*)(smem + o.xpo);
  float*   B4   = (float*)(smem + o.b4);
  float*   NRM  = (float*)(smem + o.nrm);
  float*   L2R  = (float*)(smem + o.l2r);
  float*   SLP  = (float*)(smem + o.slp);

  const int tid  = (int)threadIdx.x;
  const int bid  = (int)blockIdx.x;
  const int lane = tid & 63;
  const int wv   = tid >> 6;
  const int rows2 = (bid < NL2B) ? 4 : 0;              // uniform l2 ownership
  const int r2s   = bid * 4;
  bool dead = false;

  int lrows[4] = {0,0,0,0}, grows[4] = {0,0,0,0};
  int nr = 0;
#pragma unroll
  for (int j = 0; j < 4; ++j) {
    int row = wv + 8*j;
    if (row < 30) { int u = row/3, g = row - 3*u;
      lrows[nr] = row; grows[nr] = g*HID + bid*UPB + u; ++nr; }
  }

  // ---------------- one-time staging ----------------
  for (int i = tid; i < rows2*192; i += NTHR) { int rl = i/192, rem = i - rl*192;
    W3S[i] = p.W3[(size_t)rem*768 + (r2s + rl)]; }
  for (int i = tid; i < 240; i += NTHR) CS[i] = p.C[i];
  if (tid < 16) AS[tid] = p.A[tid];
  for (int i = tid; i < 192; i += NTHR) B3S[i] = p.b3[i];
  if (tid < rows2) B2S[tid] = p.b2[r2s + tid];
  if (tid < 30) {
    int u = tid/3, g = tid - 3*u, ug = bid*UPB + u;
    BIH[tid] = p.bih[g*HID + ug];
    BHH[tid] = p.bhh[g*HID + ug];
  }
  for (int i = tid; i < HID; i += NTHR) HS[i] = p.h0[i];
  // own-unit hidden state held in a register (tid < UPB only).
  float myh = (tid < UPB) ? p.h0[(size_t)bid*UPB + tid] : 0.f;
  if (p.resident) {
    const int kd = KRES >> 2;                   // W_ih resident cols from fp8 ws
    uint32_t* W32 = (uint32_t*)WIHR;
    for (int i = tid; i < 30*kd; i += NTHR) {
      int row = i / kd, c = i - row*kd;
      int u = row/3, g = row - 3*u, gr = g*HID + bid*UPB + u;
      W32[i] = ((const uint32_t*)p.wih8)[(size_t)gr*(KIH/4) + c];
    }
    for (int i = tid; i < 30*KHH; i += NTHR) {  // W_hh rows f32->fp8
      int row = i / KHH, k = i - row*KHH;
      int u = row/3, g = row - 3*u, gr = g*HID + bid*UPB + u;
      WHHR[i] = f2fp8(p.Whh[(size_t)gr*KHH + k]);
    }
    for (int i = tid; i < rows2*HID; i += NTHR) { // W2 slice f32->fp8
      int rl = i / HID, k = i - rl*HID;
      W2S[i] = f2fp8(p.W2[(size_t)(r2s+rl)*HID + k]);
    }
  }
  // streamed W_ih cols [KRES,4160) hoisted into VGPRs (constant across steps)
  uint2 pf[4][5];
#pragma unroll
  for (int j = 0; j < 4; ++j)
#pragma unroll
    for (int i = 0; i < 5; ++i) pf[j][i] = make_uint2(0u, 0u);
#pragma unroll
  for (int j = 0; j < 4; ++j) if (j < nr)
#pragma unroll
    for (int i = 0; i < 5; ++i)
      pf[j][i] = *(const uint2*)(p.wih8 + (size_t)grows[j]*KIH + KRES + i*512 + (lane<<3));
  __syncthreads();

  // CmA[j][k] = sum_m C[j,m]*A[m,k]  (48x4) -- needs CS/AS staged.
  if (tid < 192) {
    int j = tid >> 2, k = tid & 3;
    CMA[tid] = CS[j*5+0]*AS[0*4+k] + CS[j*5+1]*AS[1*4+k]
             + CS[j*5+2]*AS[2*4+k] + CS[j*5+3]*AS[3*4+k];
  }

  // l1a partial: L1S[r] = sum_{j<48} dequant(w1e[r,j]) * INN0[j]  (raw, x128)
  auto l1a_chunk = [&](int lo, int hi, int tbase, int tcnt) {
    float4 in0[12];
#pragma unroll
    for (int c = 0; c < 12; ++c) in0[c] = ((const float4*)INN0)[c];
    for (int r = lo + (tid - tbase); r < hi; r += tcnt) {
      const uint4* wp = (const uint4*)(p.w1e + (size_t)r*64);
      uint4 w0 = wp[0], w1 = wp[1], w2 = wp[2];
      float acc = 0.f;
      acc = fma16(w0, in0[0], in0[1], in0[2],  in0[3],  acc);
      acc = fma16(w1, in0[4], in0[5], in0[6],  in0[7],  acc);
      acc = fma16(w2, in0[8], in0[9], in0[10], in0[11], acc);
      L1S[r] = acc;
    }
  };

  // post-reduce finish: l1 = ReLU(((l1a - W4.D)/n0 + wdx.(D/n1) + b1)*INVWS)
  auto l1_finish = [&]() {
    float d0 = DXS[0], d1 = DXS[1], d2 = DXS[2], d3 = DXS[3];
    float invn0 = 1.f / NRM[0], invn1 = 1.f / NRM[1];
    float n0 = d0*invn1, n1 = d1*invn1, n2 = d2*invn1, n3 = d3*invn1;
    for (int r = tid; r < KIH; r += NTHR) {
      uint4 w = *(const uint4*)(p.w1e + (size_t)r*64 + 48);
      v2f dq0 = __builtin_amdgcn_cvt_pk_f32_fp8((int)w.x, false);
      v2f dq1 = __builtin_amdgcn_cvt_pk_f32_fp8((int)w.x, true);
      v2f bq  = __builtin_amdgcn_cvt_pk_f32_fp8((int)w.y, false);
      float2 c01 = __half22float2(*(const __half2*)&w.z);
      float2 c23 = __half22float2(*(const __half2*)&w.w);
      float corr = c01.x*d0 + c01.y*d1 + c23.x*d2 + c23.y*d3;
      float acc = (L1S[r] - corr) * invn0
                + dq0.x*n0 + dq0.y*n1 + dq1.x*n2 + dq1.y*n3 + bq.x;
      L1S[r] = fmaxf(acc * INVWS, 0.f);
    }
  };

  auto ghh = [&]() {                             // W_hh @ HS -> GHS
    float acc[4] = {0,0,0,0};
    if (p.resident) dot8_lds(HS, WHHR, KHH, KHH, lrows, nr, lane, acc);
    else            dotf_glb(HS, p.Whh, KHH, KHH, grows, nr, lane, acc);
#pragma unroll
    for (int m = 32; m >= 1; m >>= 1)
#pragma unroll
      for (int j = 0; j < 4; ++j) acc[j] += __shfl_xor(acc[j], m, 64);
    if (lane == 0)
#pragma unroll
      for (int j = 0; j < 4; ++j) if (j < nr) GHS[lrows[j]] = acc[j];
  };

  // ---------------- pre-loop (step 0 prep, Delta = 0) ----------------
  if (tid < 4) { XPO[tid] = p.x0[tid]; DXS[tid] = 0.f; }
  __syncthreads();
  if (tid < 4) {
    float s = 0;
#pragma unroll
    for (int j = 0; j < 4; ++j) s += AS[tid*4 + j] * XPO[j];
    XPRI[tid] = s;
  }
  __syncthreads();
  if (tid < 48) {
    float s = CS[tid*5 + 4];
#pragma unroll
    for (int k = 0; k < 4; ++k) s += CS[tid*5 + k] * XPRI[k];
    float i0 = p.y[(size_t)tid*TSEQ + 0] - s;
    INN0[tid] = i0; INNS[tid] = i0;
  } else if (tid >= 64 && tid < 68) {
    int k = tid - 64; float s = 0;
#pragma unroll
    for (int j = 0; j < 4; ++j) s += AS[k*4 + j] * XPRI[j];
    XQ[k] = s;                                   // A @ xprior(0), for INN0(1)
  }
  __syncthreads();
  // norms + B4 + TS for step 0
  if (wv == 0) {
    float q = (lane < 48) ? INNS[lane]*INNS[lane] : 0.f;
#pragma unroll
    for (int m = 32; m >= 1; m >>= 1) q += __shfl_xor(q, m, 64);
    if (lane == 0) NRM[0] = fmaxf(sqrtf(q), 1e-12f);
  } else if (wv == 1) {
    float q = (lane < 4) ? DXS[lane]*DXS[lane] : 0.f;
#pragma unroll
    for (int m = 32; m >= 1; m >>= 1) q += __shfl_xor(q, m, 64);
    if (lane == 0) NRM[1] = fmaxf(sqrtf(q), 1e-12f);
  }
  if (tid >= 128 && tid < 132) {
    int i = tid - 128; float s = 0;
    for (int j = 0; j < 48; ++j) s += B3S[i*48 + j] * INNS[j];
    B4[i] = s;
  }
  if (rows2 && tid >= 192 && tid < 208) {
    int idx = tid - 192, rl = idx >> 2, i = idx & 3;
    float s = 0;
    for (int j = 0; j < 48; ++j) s += W3S[rl*192 + i*48 + j] * INNS[j];
    TS[i*4 + rl] = s;
  }
  __syncthreads();
  l1a_chunk(0, KIH, 0, NTHR);
  l1_finish();                                   // same-thread rows: no barrier
  __syncthreads();
  if (tid < 48) {                                // INN0(1) from XQ
    float s = CS[tid*5 + 4];
#pragma unroll
    for (int k = 0; k < 4; ++k) s += CS[tid*5 + k] * XQ[k];
    INN0[tid] = p.y[(size_t)tid*TSEQ + 1] - s;
  }
  ghh();
  __syncthreads();

  // ---------------- main sequence ----------------
  for (int t = 0; t < TSEQ; ++t) {
    const int par = t & 1;
    const uint32_t want = (uint32_t)(t + 1);

    // ---- A: gate-dot gi = W_ih @ l1(t) ----
    {
      float acc[4] = {0,0,0,0};
      if (p.resident) dot8_lds(L1S, WIHR, KRES, KRES, lrows, nr, lane, acc);
      else            dot8_glb(L1S, p.wih8, KIH, 0, KRES, grows, nr, lane, acc);
#pragma unroll
      for (int i = 0; i < 5; ++i) {              // VGPR-held streamed cols
        const float4 a0 = ((const float4*)(L1S + KRES + i*512))[lane*2];
        const float4 a1 = ((const float4*)(L1S + KRES + i*512))[lane*2 + 1];
#pragma unroll
        for (int j = 0; j < 4; ++j) if (j < nr) {
          uint2 w = pf[j][i];
          v2f l0 = __builtin_amdgcn_cvt_pk_f32_fp8((int)w.x, false);
          v2f h0 = __builtin_amdgcn_cvt_pk_f32_fp8((int)w.x, true);
          v2f l1v = __builtin_amdgcn_cvt_pk_f32_fp8((int)w.y, false);
          v2f h1 = __builtin_amdgcn_cvt_pk_f32_fp8((int)w.y, true);
          acc[j] = fmaf(l0.x, a0.x, acc[j]); acc[j] = fmaf(l0.y, a0.y, acc[j]);
          acc[j] = fmaf(h0.x, a0.z, acc[j]); acc[j] = fmaf(h0.y, a0.w, acc[j]);
          acc[j] = fmaf(l1v.x, a1.x, acc[j]); acc[j] = fmaf(l1v.y, a1.y, acc[j]);
          acc[j] = fmaf(h1.x, a1.z, acc[j]); acc[j] = fmaf(h1.y, a1.w, acc[j]);
        }
      }
#pragma unroll
      for (int m = 32; m >= 1; m >>= 1)
#pragma unroll
        for (int j = 0; j < 4; ++j) acc[j] += __shfl_xor(acc[j], m, 64);
      if (lane == 0)
#pragma unroll
        for (int j = 0; j < 4; ++j) if (j < nr) GIS[lrows[j]] = acc[j];
    }
    __syncthreads();

    // ---- B: h(t) + fire-and-forget tagged publish (tid 0..9) ----
    if (tid < UPB) {
      int r0 = tid*3;
      float gi0 = GIS[r0+0]*INVWS + BIH[r0+0], gh0 = GHS[r0+0]*INVWS + BHH[r0+0];
      float gi1 = GIS[r0+1]*INVWS + BIH[r0+1], gh1 = GHS[r0+1]*INVWS + BHH[r0+1];
      float gi2 = GIS[r0+2]*INVWS + BIH[r0+2], gh2 = GHS[r0+2]*INVWS + BHH[r0+2];
      float rg = 1.f/(1.f + expf(-(gi0+gh0)));
      float zg = 1.f/(1.f + expf(-(gi1+gh1)));
      float ng = tanhf(gi2 + rg*gh2);
      float hnew = (1.f - zg)*ng + zg*myh;
      myh = hnew;
      pub64(p.hbp + (((size_t)par*NBLK + bid) << 4) + tid, want, hnew);
    }

    // ---- C: waves 0-3 poll h -> HS ; waves 4-7 l1a rows [0,CH0) ----
    if (wv < 4) {
      int idx = (wv << 6) | lane;
      if (idx < NBLK) {
        float v[10];
        poll_pkt<10>(p.hbp + (((size_t)par*NBLK + idx) << 4), want, v, dead);
#pragma unroll
        for (int k = 0; k < 10; ++k) HS[idx*10 + k] = v[k];
      }
    } else if (t + 1 < TSEQ) {
      l1a_chunk(0, CH0, 256, 256);
    }
    __syncthreads();

    // ---- D: waves 4-7 l2 rows ; waves 0-3 l1a rows [CH0,CH1) ----
    if (rows2 && wv >= 4) {
      const int rl = wv - 4;
      float a2 = 0.f;
      if (p.resident) {
        int kb = 0;
        for (; kb + 256 <= HID; kb += 256) {
          const float4 a = ((const float4*)(HS + kb))[lane];
          uint32_t wb = *(const uint32_t*)(W2S + rl*HID + kb + (lane<<2));
          v2f lo = __builtin_amdgcn_cvt_pk_f32_fp8((int)wb, false);
          v2f hi = __builtin_amdgcn_cvt_pk_f32_fp8((int)wb, true);
          a2 = fmaf(lo.x, a.x, a2); a2 = fmaf(lo.y, a.y, a2);
          a2 = fmaf(hi.x, a.z, a2); a2 = fmaf(hi.y, a.w, a2);
        }
        if ((lane << 2) < HID - kb) {
          const float4 a = ((const float4*)(HS + kb))[lane];
          uint32_t wb = *(const uint32_t*)(W2S + rl*HID + kb + (lane<<2));
          v2f lo = __builtin_amdgcn_cvt_pk_f32_fp8((int)wb, false);
          v2f hi = __builtin_amdgcn_cvt_pk_f32_fp8((int)wb, true);
          a2 = fmaf(lo.x, a.x, a2); a2 = fmaf(lo.y, a.y, a2);
          a2 = fmaf(hi.x, a.z, a2); a2 = fmaf(hi.y, a.w, a2);
        }
        a2 *= INVWS;
      } else {
        for (int k = lane; k < HID; k += 64)
          a2 = fmaf(p.W2[(size_t)(r2s+rl)*HID + k], HS[k], a2);
      }
#pragma unroll
      for (int m = 32; m >= 1; m >>= 1) a2 += __shfl_xor(a2, m, 64);
      if (lane == 0) L2R[rl] = fmaxf(a2 + B2S[rl], 0.f);
    } else if (wv < 4 && t + 1 < TSEQ) {
      l1a_chunk(CH0, CH1, 0, 256);
    }
    __syncthreads();
    if (rows2 && tid < 4) {                      // publish 4 slot words
      float cp = L2R[0]*TS[tid*4+0] + L2R[1]*TS[tid*4+1]
               + L2R[2]*TS[tid*4+2] + L2R[3]*TS[tid*4+3];
      pub64(p.slt + (((size_t)par*NBLK + bid) << 3) + tid, want, cp);
    }

    // ---- E: ghh(t+1) + l1a rows [CH1,KIH) (all waves; covers slot flight) --
    ghh();
    if (t + 1 < TSEQ) l1a_chunk(CH1, KIH, 0, NTHR);

    // ---- F: slot reduce (waves 0-2: 192 packets) ----
    if (wv < 3) {
      int idx = (wv << 6) | lane;
      float v[4];
      poll_pkt<4>(p.slt + (((size_t)par*NBLK + idx) << 3), want, v, dead);
      float s0 = v[0], s1 = v[1], s2 = v[2], s3 = v[3];
#pragma unroll
      for (int m = 32; m >= 1; m >>= 1) {
        s0 += __shfl_xor(s0, m, 64); s1 += __shfl_xor(s1, m, 64);
        s2 += __shfl_xor(s2, m, 64); s3 += __shfl_xor(s3, m, 64);
      }
      if (lane == 0) {
        SLP[wv*4+0] = s0; SLP[wv*4+1] = s1; SLP[wv*4+2] = s2; SLP[wv*4+3] = s3;
      }
    }
    __syncthreads();

    // ---- G: posterior ----
    if (tid < 4) {
      float c = SLP[tid] + SLP[4 + tid] + SLP[8 + tid];
      float xp = XPRI[tid] + (c + B4[tid]) * 1e-4f;
      XPO[tid] = xp;
      if (bid == 0) p.out[(size_t)tid*TSEQ + t] = xp;
    }
    __syncthreads();

    // ---- tail: prep step t+1 ----
    if (t + 1 < TSEQ) {
      // T1: dx, new prior
      if (tid < 4) {
        float xo = XPO[tid];
        DXS[tid] = xo - XPRI[tid];
        float s = 0;
#pragma unroll
        for (int j = 0; j < 4; ++j) s += AS[tid*4 + j] * XPO[j];
        XPRI[tid] = s;
      }
      __syncthreads();
      // T2: inn = inn0 - CmA@dx ; XQ = A@xprior(t+1)
      if (tid < 48) {
        float dv = CMA[tid*4+0]*DXS[0] + CMA[tid*4+1]*DXS[1]
                 + CMA[tid*4+2]*DXS[2] + CMA[tid*4+3]*DXS[3];
        INNS[tid] = INN0[tid] - dv;
      } else if (tid >= 64 && tid < 68) {
        int k = tid - 64; float s = 0;
#pragma unroll
        for (int j = 0; j < 4; ++j) s += AS[k*4 + j] * XPRI[j];
        XQ[k] = s;
      }
      __syncthreads();
      // T3: norms + B4 + TS
      if (wv == 0) {
        float q = (lane < 48) ? INNS[lane]*INNS[lane] : 0.f;
#pragma unroll
        for (int m = 32; m >= 1; m >>= 1) q += __shfl_xor(q, m, 64);
        if (lane == 0) NRM[0] = fmaxf(sqrtf(q), 1e-12f);
      } else if (wv == 1) {
        float q = (lane < 4) ? DXS[lane]*DXS[lane] : 0.f;
#pragma unroll
        for (int m = 32; m >= 1; m >>= 1) q += __shfl_xor(q, m, 64);
        if (lane == 0) NRM[1] = fmaxf(sqrtf(q), 1e-12f);
      }
      if (tid >= 128 && tid < 132) {
        int i = tid - 128; float s = 0;
        for (int j = 0; j < 48; ++j) s += B3S[i*48 + j] * INNS[j];
        B4[i] = s;
      }
      if (rows2 && tid >= 192 && tid < 208) {
        int idx = tid - 192, rl = idx >> 2, i = idx & 3;
        float s = 0;
        for (int j = 0; j < 48; ++j) s += W3S[rl*192 + i*48 + j] * INNS[j];
        TS[i*4 + rl] = s;
      }
      __syncthreads();
      // T4: finish l1(t+1) in place ; INN0(t+2) from XQ
      if (tid < 48 && t + 2 < TSEQ) {
        float s = CS[tid*5 + 4];
#pragma unroll
        for (int k = 0; k < 4; ++k) s += CS[tid*5 + k] * XQ[k];
        INN0[tid] = p.y[(size_t)tid*TSEQ + (t+2)] - s;
      }
      l1_finish();
      __syncthreads();
    }
  }
}

// f32 -> fp8 e4m3 (x128), 4 elements per thread (W_ih full).
extern "C" __global__ void knet_cvt_fp8(const float* __restrict__ src,
                                        uint8_t* __restrict__ dst, long n4) {
  long stride = (long)gridDim.x * blockDim.x;
  for (long i = (long)blockIdx.x*blockDim.x + threadIdx.x; i < n4; i += stride) {
    float4 v = ((const float4*)src)[i];
    float a0 = fminf(fmaxf(v.x * 128.f, -448.f), 448.f);
    float a1 = fminf(fmaxf(v.y * 128.f, -448.f), 448.f);
    float a2 = fminf(fmaxf(v.z * 128.f, -448.f), 448.f);
    float a3 = fminf(fmaxf(v.w * 128.f, -448.f), 448.f);
    int pk = __builtin_amdgcn_cvt_pk_fp8_f32(a0, a1, 0, false);
    pk = __builtin_amdgcn_cvt_pk_fp8_f32(a2, a3, pk, true);
    ((uint32_t*)dst)[i] = (uint32_t)pk;
  }
}

// Build W1ext fp8: row r = [W1[r,0:52], b1[r], pad] * 128, 64 B/row.
// Pad bytes 56-63 carry W4[r,0:4] as f16, where
//   W4[r,k] = sum_{j<48} dequant(fp8(W1[r,j]*128)) * (C[:, :4]@A)[j,k].
extern "C" __global__ void knet_build_w1e(const float* __restrict__ W1,
                                          const float* __restrict__ b1,
                                          const float* __restrict__ Cm,
                                          const float* __restrict__ Am,
                                          uint8_t* __restrict__ dst) {
  int r = blockIdx.x * blockDim.x + threadIdx.x;
  if (r >= KIH) return;
  float v[64];
#pragma unroll 13
  for (int q = 0; q < 13; ++q) {
    float4 w = ((const float4*)(W1 + (size_t)r*52))[q];
    v[q*4+0] = w.x; v[q*4+1] = w.y; v[q*4+2] = w.z; v[q*4+3] = w.w;
  }
  v[52] = b1[r];
  for (int i = 53; i < 64; ++i) v[i] = 0.f;
  uint32_t out[16];
#pragma unroll 16
  for (int d = 0; d < 16; ++d) {
    float a0 = fminf(fmaxf(v[d*4+0] * 128.f, -448.f), 448.f);
    float a1 = fminf(fmaxf(v[d*4+1] * 128.f, -448.f), 448.f);
    float a2 = fminf(fmaxf(v[d*4+2] * 128.f, -448.f), 448.f);
    float a3 = fminf(fmaxf(v[d*4+3] * 128.f, -448.f), 448.f);
    int pk = __builtin_amdgcn_cvt_pk_fp8_f32(a0, a1, 0, false);
    pk = __builtin_amdgcn_cvt_pk_fp8_f32(a2, a3, pk, true);
    out[d] = (uint32_t)pk;
  }
  // W4 from the QUANTIZED weights (exact values the main kernel dots).
  float w4[4];
#pragma unroll
  for (int k = 0; k < 4; ++k) {
    float a0 = Am[0*4+k], a1 = Am[1*4+k], a2 = Am[2*4+k], a3 = Am[3*4+k];
    float acc = 0.f;
    for (int q = 0; q < 12; ++q) {
      v2f lo = __builtin_amdgcn_cvt_pk_f32_fp8((int)out[q], false);
      v2f hi = __builtin_amdgcn_cvt_pk_f32_fp8((int)out[q], true);
      int j = q * 4;
      float c0 = Cm[(j+0)*5+0]*a0 + Cm[(j+0)*5+1]*a1 + Cm[(j+0)*5+2]*a2 + Cm[(j+0)*5+3]*a3;
      float c1 = Cm[(j+1)*5+0]*a0 + Cm[(j+1)*5+1]*a1 + Cm[(j+1)*5+2]*a2 + Cm[(j+1)*5+3]*a3;
      float c2 = Cm[(j+2)*5+0]*a0 + Cm[(j+2)*5+1]*a1 + Cm[(j+2)*5+2]*a2 + Cm[(j+2)*5+3]*a3;
      float c3 = Cm[(j+3)*5+0]*a0 + Cm[(j+3)*5+1]*a1 + Cm[(j+3)*5+2]*a2 + Cm[(j+3)*5+3]*a3;
      acc += lo.x*c0 + lo.y*c1 + hi.x*c2 + hi.y*c3;
    }
    w4[k] = acc;
  }
  __half2 h01 = __floats2half2_rn(w4[0], w4[1]);
  __half2 h23 = __floats2half2_rn(w4[2], w4[3]);
  out[14] = *(const uint32_t*)&h01;
  out[15] = *(const uint32_t*)&h23;
  uint4* dp = (uint4*)(dst + (size_t)r*64);
#pragma unroll 4
  for (int q = 0; q < 4; ++q)
    dp[q] = make_uint4(out[q*4+0], out[q*4+1], out[q*4+2], out[q*4+3]);
}

extern "C" void kernel_launch(void* const* d_in, const int* in_sizes, int n_in,
                              void* d_out, int out_size, void* d_ws, size_t ws_size,
                              hipStream_t stream)
{
  if (ws_size < (size_t)WS_END) return;   // 29.3 MB (proven available)
  uint8_t* ws = (uint8_t*)d_ws;

  knet_cvt_fp8<<<2048, 256, 0, stream>>>((const float*)d_in[7], ws + WS_WIH8,
                                         (long)G3*KIH/4);
  knet_build_w1e<<<(KIH + 255)/256, 256, 0, stream>>>(
      (const float*)d_in[5], (const float*)d_in[6],
      (const float*)d_in[1], (const float*)d_in[0], ws + WS_W1E);
  // no memset needed: word tags are exact-match (t+1); 0xAA poison never matches

  int resident = 1;
  Offs o = mkoffs(resident);
  hipError_t e = hipFuncSetAttribute((const void*)knet_main,
                                     hipFuncAttributeMaxDynamicSharedMemorySize,
                                     o.total);
  if (e != hipSuccess) {
    resident = 0; o = mkoffs(resident);
    (void)hipFuncSetAttribute((const void*)knet_main,
                              hipFuncAttributeMaxDynamicSharedMemorySize, o.total);
  }

  Params p;
  p.A   = (const float*)d_in[0];  p.C   = (const float*)d_in[1];
  p.x0  = (const float*)d_in[2];  p.h0  = (const float*)d_in[3];
  p.y   = (const float*)d_in[4];
  p.W1  = (const float*)d_in[5];  p.b1  = (const float*)d_in[6];
  p.Wih = (const float*)d_in[7];  p.Whh = (const float*)d_in[8];
  p.bih = (const float*)d_in[9];  p.bhh = (const float*)d_in[10];
  p.W2  = (const float*)d_in[11]; p.b2  = (const float*)d_in[12];
  p.W3  = (const float*)d_in[13]; p.b3  = (const float*)d_in[14];
  p.wih8 = ws + WS_WIH8;
  p.w1e  = ws + WS_W1E;
  p.hbp  = (uint64_t*)(ws + WS_HBP);
  p.slt  = (uint64_t*)(ws + WS_SLT);
  p.out  = (float*)d_out;
  p.resident = resident;

  knet_main<<<NBLK, NTHR, (size_t)o.total, stream>>>(p);
}

// Round 4
// 10417.390 us; speedup vs baseline: 1.0217x; 1.0217x over previous
//
// KalmanNetNN persistent kernel, MI355X (gfx950).
// R12: revert R11's window-hiding (barrier-gated fill > wait: +2.1ms) and the
//   gated poll (R10: +235us). Back to R8's proven phase structure:
//   full-packet poll, single-pass l1, idle C-window. Keep myh (register own-h,
//   post-B barrier dropped).
// New: wave-0 fused tail. R8's post-F stretch (posterior -> dx/prior -> inn ->
//   norms -> KN/B4/TS) was 5 block-barriers of 4-48-lane ops. All of it now
//   runs on wave 0 wave-synchronously: shuffles for the 4-dim state, butterfly
//   reductions for both norms, B4 (lanes 0-3) and TS (lanes 8-23) in parallel.
//   DS ops are in-order within a wave -> no barrier until KN must be visible
//   to all waves for l1. Per-step barriers: ~10 -> 6.
//   xpri/B4 become wave-0 registers (myXpri/myB4); XPO/DXS LDS pre-loop only.
// Predicted: step 16.2 -> 15.4-16.1 us => 7.9-8.25 ms. VGPR ~128, FETCH flat.

#include <hip/hip_runtime.h>
#include <stdint.h>
#include <stddef.h>

typedef float v2f __attribute__((ext_vector_type(2)));

#define HID   2320
#define G3    6960
#define KIH   4160
#define KHH   2320
#define NBLK  232
#define NL2B  192              // blocks owning l2 rows (4 each = 768)
#define NTHR  512
#define UPB   10
#define TSEQ  512
#define KRES  1600
#define INVWS (1.0f/128.0f)
#define SPINCAP (1u<<17)

// ---------------- workspace layout (bytes) ----------------
#define WS_WIH8 0L            // 6960*4160 fp8
#define WS_W1E  28953600L     // 4160*64 fp8 W1ext (52 w + b1 + pad)
#define WS_HBP  29219840L     // 2 x 232 x 128B h packets (10 tagged words)
#define WS_SLT  29279232L     // 2 x 232 x 64B slot packets (4 tagged words)
#define WS_END  29308928L

struct Offs {
  int l1s, hs, wih, whh, w2s, w3s, cs, as_, b3s, bih, bhh, b2s, gis, ghs,
      ts, inn, kn, dxs, xpri, xpo, b4, nrm, l2r, slp;
  int total;
};

__host__ __device__ inline Offs mkoffs(int res) {
  Offs o; int p = 0;
#define ALLOC(name, bytes) { p = (p + 15) & ~15; o.name = p; p += (bytes); }
  ALLOC(l1s, KIH*4) ALLOC(hs, HID*4)
  ALLOC(wih, res ? 30*KRES : 16) ALLOC(whh, res ? 30*KHH : 16)
  ALLOC(w2s, res ? 4*HID : 16)
  ALLOC(w3s, 16*48*4) ALLOC(cs, 240*4) ALLOC(as_, 64) ALLOC(b3s, 192*4)
  ALLOC(bih, 120) ALLOC(bhh, 120) ALLOC(b2s, 16)
  ALLOC(gis, 120) ALLOC(ghs, 120)
  ALLOC(ts, 64) ALLOC(inn, 192) ALLOC(kn, 256)
  ALLOC(dxs, 16) ALLOC(xpri, 16) ALLOC(xpo, 16) ALLOC(b4, 16) ALLOC(nrm, 16)
  ALLOC(l2r, 16) ALLOC(slp, 64)
#undef ALLOC
  o.total = (p + 63) & ~63;
  return o;
}

struct Params {
  const float *A, *C, *x0, *h0, *y, *W1, *b1, *Wih, *Whh, *bih, *bhh, *W2, *b2, *W3, *b3;
  const uint8_t *wih8, *w1e;
  uint64_t *hbp, *slt;
  float *out;
  int resident;
};

__device__ __forceinline__ uint8_t f2fp8(float v) {
  v = fminf(fmaxf(v * 128.f, -448.f), 448.f);
  int pk = __builtin_amdgcn_cvt_pk_fp8_f32(v, v, 0, false);
  return (uint8_t)(pk & 0xff);
}

// fire-and-forget tagged publish: one self-validating 8B word.
__device__ __forceinline__ void pub64(uint64_t* a, uint32_t tag, float v) {
  uint64_t w = ((uint64_t)tag << 32) | (uint64_t)__float_as_uint(v);
  __hip_atomic_store(a, w, __ATOMIC_RELAXED, __HIP_MEMORY_SCOPE_AGENT);
}

// full-packet poll (R8 form): all N tagged words each round, hot 8 rounds.
template<int N>
__device__ __forceinline__ void poll_pkt(const uint64_t* base, uint32_t want,
                                         float* out, bool& dead) {
  uint64_t v[N];
  uint32_t spins = 0;
  for (;;) {
    bool ok = true;
#pragma unroll
    for (int k = 0; k < N; ++k)
      v[k] = __hip_atomic_load(base + k, __ATOMIC_RELAXED, __HIP_MEMORY_SCOPE_AGENT);
#pragma unroll
    for (int k = 0; k < N; ++k) ok &= ((uint32_t)(v[k] >> 32) == want);
    if (ok || dead) break;
    ++spins;
    if (spins > 8) __builtin_amdgcn_s_sleep(2);
    if (spins > SPINCAP) dead = true;
  }
#pragma unroll
  for (int k = 0; k < N; ++k) out[k] = __uint_as_float((uint32_t)v[k]);
}

// 16-wide fp8 dot fragment: acc += dot(fp8x16(w), [a0 a1 a2 a3])
__device__ __forceinline__ float fma16(uint4 w, float4 a0, float4 a1,
                                       float4 a2, float4 a3, float acc) {
  v2f l0 = __builtin_amdgcn_cvt_pk_f32_fp8((int)w.x, false);
  v2f h0 = __builtin_amdgcn_cvt_pk_f32_fp8((int)w.x, true);
  v2f l1 = __builtin_amdgcn_cvt_pk_f32_fp8((int)w.y, false);
  v2f h1 = __builtin_amdgcn_cvt_pk_f32_fp8((int)w.y, true);
  v2f l2 = __builtin_amdgcn_cvt_pk_f32_fp8((int)w.z, false);
  v2f h2 = __builtin_amdgcn_cvt_pk_f32_fp8((int)w.z, true);
  v2f l3 = __builtin_amdgcn_cvt_pk_f32_fp8((int)w.w, false);
  v2f h3 = __builtin_amdgcn_cvt_pk_f32_fp8((int)w.w, true);
  acc = fmaf(l0.x,a0.x,acc); acc = fmaf(l0.y,a0.y,acc);
  acc = fmaf(h0.x,a0.z,acc); acc = fmaf(h0.y,a0.w,acc);
  acc = fmaf(l1.x,a1.x,acc); acc = fmaf(l1.y,a1.y,acc);
  acc = fmaf(h1.x,a1.z,acc); acc = fmaf(h1.y,a1.w,acc);
  acc = fmaf(l2.x,a2.x,acc); acc = fmaf(l2.y,a2.y,acc);
  acc = fmaf(h2.x,a2.z,acc); acc = fmaf(h2.y,a2.w,acc);
  acc = fmaf(l3.x,a3.x,acc); acc = fmaf(l3.y,a3.y,acc);
  acc = fmaf(h3.x,a3.z,acc); acc = fmaf(h3.y,a3.w,acc);
  return acc;
}

// fp8 row-dot, LDS weights, <=4 rows/wave, lanes split K.
__device__ __forceinline__ void dot8_lds(
    const float* __restrict__ acts, const uint8_t* __restrict__ w, int stride,
    int K, const int* lrows, int nr, int lane, float acc[4])
{
  int kb = 0;
  for (; kb + 256 <= K; kb += 256) {
    const float4 a = ((const float4*)(acts + kb))[lane];
#pragma unroll
    for (int j = 0; j < 4; ++j) if (j < nr) {
      uint32_t wb = *(const uint32_t*)(w + (size_t)lrows[j]*stride + kb + (lane<<2));
      v2f lo = __builtin_amdgcn_cvt_pk_f32_fp8((int)wb, false);
      v2f hi = __builtin_amdgcn_cvt_pk_f32_fp8((int)wb, true);
      acc[j] = fmaf(lo.x, a.x, acc[j]); acc[j] = fmaf(lo.y, a.y, acc[j]);
      acc[j] = fmaf(hi.x, a.z, acc[j]); acc[j] = fmaf(hi.y, a.w, acc[j]);
    }
  }
  int rem = K - kb;
  if ((lane << 2) < rem) {
    const float4 a = ((const float4*)(acts + kb))[lane];
#pragma unroll
    for (int j = 0; j < 4; ++j) if (j < nr) {
      uint32_t wb = *(const uint32_t*)(w + (size_t)lrows[j]*stride + kb + (lane<<2));
      v2f lo = __builtin_amdgcn_cvt_pk_f32_fp8((int)wb, false);
      v2f hi = __builtin_amdgcn_cvt_pk_f32_fp8((int)wb, true);
      acc[j] = fmaf(lo.x, a.x, acc[j]); acc[j] = fmaf(lo.y, a.y, acc[j]);
      acc[j] = fmaf(hi.x, a.z, acc[j]); acc[j] = fmaf(hi.y, a.w, acc[j]);
    }
  }
}

// fp8 row-dot, global weights, cols [K0,K).
__device__ __forceinline__ void dot8_glb(
    const float* __restrict__ acts, const uint8_t* __restrict__ gw, int gstride,
    int K0, int K, const int* grows, int nr, int lane, float acc[4])
{
  int kb = K0;
  for (; kb + 512 <= K; kb += 512) {
    const float4 a0 = ((const float4*)(acts + kb))[lane*2];
    const float4 a1 = ((const float4*)(acts + kb))[lane*2 + 1];
#pragma unroll
    for (int j = 0; j < 4; ++j) if (j < nr) {
      uint2 wb = *(const uint2*)(gw + (size_t)grows[j]*gstride + kb + (lane<<3));
      v2f l0 = __builtin_amdgcn_cvt_pk_f32_fp8((int)wb.x, false);
      v2f h0 = __builtin_amdgcn_cvt_pk_f32_fp8((int)wb.x, true);
      v2f l1 = __builtin_amdgcn_cvt_pk_f32_fp8((int)wb.y, false);
      v2f h1 = __builtin_amdgcn_cvt_pk_f32_fp8((int)wb.y, true);
      acc[j] = fmaf(l0.x, a0.x, acc[j]); acc[j] = fmaf(l0.y, a0.y, acc[j]);
      acc[j] = fmaf(h0.x, a0.z, acc[j]); acc[j] = fmaf(h0.y, a0.w, acc[j]);
      acc[j] = fmaf(l1.x, a1.x, acc[j]); acc[j] = fmaf(l1.y, a1.y, acc[j]);
      acc[j] = fmaf(h1.x, a1.z, acc[j]); acc[j] = fmaf(h1.y, a1.w, acc[j]);
    }
  }
  for (int e = kb + lane; e < K; e += 64) {
    float a = acts[e];
#pragma unroll
    for (int j = 0; j < 4; ++j) if (j < nr) {
      v2f lo = __builtin_amdgcn_cvt_pk_f32_fp8(
          (int)(uint32_t)gw[(size_t)grows[j]*gstride + e], false);
      acc[j] = fmaf(lo.x, a, acc[j]);
    }
  }
}

// f32 row-dot, global weights (fallback ghh).
__device__ __forceinline__ void dotf_glb(
    const float* __restrict__ acts, const float* __restrict__ gw, int gstride,
    int K, const int* grows, int nr, int lane, float acc[4])
{
  for (int k = lane; k < K; k += 64) {
    float a = acts[k];
#pragma unroll
    for (int j = 0; j < 4; ++j) if (j < nr)
      acc[j] = fmaf(gw[(size_t)grows[j]*gstride + k], a, acc[j]);
  }
}

extern "C" __global__ void __launch_bounds__(NTHR, 2) knet_main(Params p)
{
  extern __shared__ char smem[];
  const Offs o = mkoffs(p.resident);
  float*   L1S  = (float*)(smem + o.l1s);
  float*   HS   = (float*)(smem + o.hs);
  uint8_t* WIHR = (uint8_t*)(smem + o.wih);
  uint8_t* WHHR = (uint8_t*)(smem + o.whh);
  uint8_t* W2S  = (uint8_t*)(smem + o.w2s);
  float*   W3S  = (float*)(smem + o.w3s);
  float*   CS   = (float*)(smem + o.cs);
  float*   AS   = (float*)(smem + o.as_);
  float*   B3S  = (float*)(smem + o.b3s);
  float*   BIH  = (float*)(smem + o.bih);
  float*   BHH  = (float*)(smem + o.bhh);
  float*   B2S  = (float*)(smem + o.b2s);
  float*   GIS  = (float*)(smem + o.gis);
  float*   GHS  = (float*)(smem + o.ghs);
  float*   TS   = (float*)(smem + o.ts);
  float*   INNS = (float*)(smem + o.inn);
  float*   KN   = (float*)(smem + o.kn);
  float*   DXS  = (float*)(smem + o.dxs);
  float*   XPRI = (float*)(smem + o.xpri);
  float*   XPO  = (float*)(smem + o.xpo);
  float*   B4   = (float*)(smem + o.b4);
  float*   NRM  = (float*)(smem + o.nrm);
  float*   L2R  = (float*)(smem + o.l2r);
  float*   SLP  = (float*)(smem + o.slp);

  const int tid  = (int)threadIdx.x;
  const int bid  = (int)blockIdx.x;
  const int lane = tid & 63;
  const int wv   = tid >> 6;
  const int rows2 = (bid < NL2B) ? 4 : 0;              // uniform l2 ownership
  const int r2s   = bid * 4;
  bool dead = false;

  int lrows[4] = {0,0,0,0}, grows[4] = {0,0,0,0};
  int nr = 0;
#pragma unroll
  for (int j = 0; j < 4; ++j) {
    int row = wv + 8*j;
    if (row < 30) { int u = row/3, g = row - 3*u;
      lrows[nr] = row; grows[nr] = g*HID + bid*UPB + u; ++nr; }
  }

  // ---------------- one-time staging ----------------
  for (int i = tid; i < rows2*192; i += NTHR) { int rl = i/192, rem = i - rl*192;
    W3S[i] = p.W3[(size_t)rem*768 + (r2s + rl)]; }
  for (int i = tid; i < 240; i += NTHR) CS[i] = p.C[i];
  if (tid < 16) AS[tid] = p.A[tid];
  for (int i = tid; i < 192; i += NTHR) B3S[i] = p.b3[i];
  if (tid < rows2) B2S[tid] = p.b2[r2s + tid];
  if (tid < 30) {
    int u = tid/3, g = tid - 3*u, ug = bid*UPB + u;
    BIH[tid] = p.bih[g*HID + ug];
    BHH[tid] = p.bhh[g*HID + ug];
  }
  for (int i = tid; i < HID; i += NTHR) HS[i] = p.h0[i];
  // own-unit hidden state held in a register (tid < UPB only).
  float myh = (tid < UPB) ? p.h0[(size_t)bid*UPB + tid] : 0.f;
  if (p.resident) {
    const int kd = KRES >> 2;                   // W_ih resident cols from fp8 ws
    uint32_t* W32 = (uint32_t*)WIHR;
    for (int i = tid; i < 30*kd; i += NTHR) {
      int row = i / kd, c = i - row*kd;
      int u = row/3, g = row - 3*u, gr = g*HID + bid*UPB + u;
      W32[i] = ((const uint32_t*)p.wih8)[(size_t)gr*(KIH/4) + c];
    }
    for (int i = tid; i < 30*KHH; i += NTHR) {  // W_hh rows f32->fp8
      int row = i / KHH, k = i - row*KHH;
      int u = row/3, g = row - 3*u, gr = g*HID + bid*UPB + u;
      WHHR[i] = f2fp8(p.Whh[(size_t)gr*KHH + k]);
    }
    for (int i = tid; i < rows2*HID; i += NTHR) { // W2 slice f32->fp8
      int rl = i / HID, k = i - rl*HID;
      W2S[i] = f2fp8(p.W2[(size_t)(r2s+rl)*HID + k]);
    }
  }
  // streamed W_ih cols [KRES,4160) hoisted into VGPRs (constant across steps)
  uint2 pf[4][5];
#pragma unroll
  for (int j = 0; j < 4; ++j)
#pragma unroll
    for (int i = 0; i < 5; ++i) pf[j][i] = make_uint2(0u, 0u);
#pragma unroll
  for (int j = 0; j < 4; ++j) if (j < nr)
#pragma unroll
    for (int i = 0; i < 5; ++i)
      pf[j][i] = *(const uint2*)(p.wih8 + (size_t)grows[j]*KIH + KRES + i*512 + (lane<<3));
  __syncthreads();

  // full single-pass l1: L1S = ReLU((W1ext @ KN) * INVWS), all waves.
  auto full_l1 = [&]() {
    float4 kn[16];
#pragma unroll
    for (int c = 0; c < 16; ++c) kn[c] = ((const float4*)KN)[c];
    for (int r = tid; r < KIH; r += NTHR) {
      const uint4* wp = (const uint4*)(p.w1e + (size_t)r*64);
      float acc = 0.f;
#pragma unroll
      for (int q = 0; q < 4; ++q) {
        uint4 w = wp[q];
        acc = fma16(w, kn[q*4+0], kn[q*4+1], kn[q*4+2], kn[q*4+3], acc);
      }
      L1S[r] = fmaxf(acc * INVWS, 0.f);
    }
  };

  auto ghh = [&]() {                             // W_hh @ HS -> GHS
    float acc[4] = {0,0,0,0};
    if (p.resident) dot8_lds(HS, WHHR, KHH, KHH, lrows, nr, lane, acc);
    else            dotf_glb(HS, p.Whh, KHH, KHH, grows, nr, lane, acc);
#pragma unroll
    for (int m = 32; m >= 1; m >>= 1)
#pragma unroll
      for (int j = 0; j < 4; ++j) acc[j] += __shfl_xor(acc[j], m, 64);
    if (lane == 0)
#pragma unroll
      for (int j = 0; j < 4; ++j) if (j < nr) GHS[lrows[j]] = acc[j];
  };

  // ---------------- pre-loop (step-0 prep, R8 form; cost irrelevant) --------
  if (tid < 4) { XPO[tid] = p.x0[tid]; DXS[tid] = 0.f; }
  __syncthreads();
  if (tid < 4) {
    float s = 0;
#pragma unroll
    for (int j = 0; j < 4; ++j) s += AS[tid*4 + j] * XPO[j];
    XPRI[tid] = s;
  }
  __syncthreads();
  if (tid < 48) {
    float s = CS[tid*5 + 4];
#pragma unroll
    for (int k = 0; k < 4; ++k) s += CS[tid*5 + k] * XPRI[k];
    INNS[tid] = p.y[(size_t)tid*TSEQ + 0] - s;
  }
  __syncthreads();
  if (wv == 0) {                                 // ||inn||
    float q = (lane < 48) ? INNS[lane]*INNS[lane] : 0.f;
#pragma unroll
    for (int m = 32; m >= 1; m >>= 1) q += __shfl_xor(q, m, 64);
    if (lane == 0) NRM[0] = fmaxf(sqrtf(q), 1e-12f);
  } else if (wv == 1) {                          // ||dx|| (= 0 at t=0)
    float q = (lane < 4) ? DXS[lane]*DXS[lane] : 0.f;
#pragma unroll
    for (int m = 32; m >= 1; m >>= 1) q += __shfl_xor(q, m, 64);
    if (lane == 0) NRM[1] = fmaxf(sqrtf(q), 1e-12f);
  }
  __syncthreads();
  if (tid < 48) KN[tid] = INNS[tid] / NRM[0];
  else if (tid < 52) KN[tid] = DXS[tid-48] / NRM[1];
  else if (tid == 52) KN[tid] = 1.0f;
  else if (tid < 64) KN[tid] = 0.0f;
  else if (tid < 68) {
    int i = tid - 64; float s = 0;
    for (int j = 0; j < 48; ++j) s += B3S[i*48 + j] * INNS[j];
    B4[i] = s;
  }
  if (rows2 && tid >= 128 && tid < 144) {
    int idx = tid - 128, rl = idx >> 2, i = idx & 3;
    float s = 0;
    for (int j = 0; j < 48; ++j) s += W3S[rl*192 + i*48 + j] * INNS[j];
    TS[i*4 + rl] = s;
  }
  __syncthreads();
  full_l1();
  ghh();
  __syncthreads();
  // wave-0 register state for the fused tail
  float myXpri = 0.f, myB4 = 0.f;
  if (wv == 0 && lane < 4) { myXpri = XPRI[lane]; myB4 = B4[lane]; }

  // ---------------- main sequence ----------------
  for (int t = 0; t < TSEQ; ++t) {
    const int par = t & 1;
    const uint32_t want = (uint32_t)(t + 1);

    // ---- A: gate-dot gi = W_ih @ l1(t) ----
    {
      float acc[4] = {0,0,0,0};
      if (p.resident) dot8_lds(L1S, WIHR, KRES, KRES, lrows, nr, lane, acc);
      else            dot8_glb(L1S, p.wih8, KIH, 0, KRES, grows, nr, lane, acc);
#pragma unroll
      for (int i = 0; i < 5; ++i) {              // VGPR-held streamed cols
        const float4 a0 = ((const float4*)(L1S + KRES + i*512))[lane*2];
        const float4 a1 = ((const float4*)(L1S + KRES + i*512))[lane*2 + 1];
#pragma unroll
        for (int j = 0; j < 4; ++j) if (j < nr) {
          uint2 w = pf[j][i];
          v2f l0 = __builtin_amdgcn_cvt_pk_f32_fp8((int)w.x, false);
          v2f h0 = __builtin_amdgcn_cvt_pk_f32_fp8((int)w.x, true);
          v2f l1v = __builtin_amdgcn_cvt_pk_f32_fp8((int)w.y, false);
          v2f h1 = __builtin_amdgcn_cvt_pk_f32_fp8((int)w.y, true);
          acc[j] = fmaf(l0.x, a0.x, acc[j]); acc[j] = fmaf(l0.y, a0.y, acc[j]);
          acc[j] = fmaf(h0.x, a0.z, acc[j]); acc[j] = fmaf(h0.y, a0.w, acc[j]);
          acc[j] = fmaf(l1v.x, a1.x, acc[j]); acc[j] = fmaf(l1v.y, a1.y, acc[j]);
          acc[j] = fmaf(h1.x, a1.z, acc[j]); acc[j] = fmaf(h1.y, a1.w, acc[j]);
        }
      }
#pragma unroll
      for (int m = 32; m >= 1; m >>= 1)
#pragma unroll
        for (int j = 0; j < 4; ++j) acc[j] += __shfl_xor(acc[j], m, 64);
      if (lane == 0)
#pragma unroll
        for (int j = 0; j < 4; ++j) if (j < nr) GIS[lrows[j]] = acc[j];
    }
    __syncthreads();

    // ---- B: h(t) + fire-and-forget tagged publish (tid 0..9) ----
    // B reads only GIS/GHS/BIH/BHH + register myh: no barrier needed before
    // C overwrites HS.
    if (tid < UPB) {
      int r0 = tid*3;
      float gi0 = GIS[r0+0]*INVWS + BIH[r0+0], gh0 = GHS[r0+0]*INVWS + BHH[r0+0];
      float gi1 = GIS[r0+1]*INVWS + BIH[r0+1], gh1 = GHS[r0+1]*INVWS + BHH[r0+1];
      float gi2 = GIS[r0+2]*INVWS + BIH[r0+2], gh2 = GHS[r0+2]*INVWS + BHH[r0+2];
      float rg = 1.f/(1.f + expf(-(gi0+gh0)));
      float zg = 1.f/(1.f + expf(-(gi1+gh1)));
      float ng = tanhf(gi2 + rg*gh2);
      float hnew = (1.f - zg)*ng + zg*myh;
      myh = hnew;
      pub64(p.hbp + (((size_t)par*NBLK + bid) << 4) + tid, want, hnew);
    }

    // ---- C: h broadcast consume -> HS (waves 0-3) ----
    if (wv < 4) {
      int idx = (wv << 6) | lane;
      if (idx < NBLK) {
        float v[10];
        poll_pkt<10>(p.hbp + (((size_t)par*NBLK + idx) << 4), want, v, dead);
#pragma unroll
        for (int k = 0; k < 10; ++k) HS[idx*10 + k] = v[k];
      }
    }
    __syncthreads();

    // ---- D: l2 rows, one per wave on waves 4-7 (blocks < NL2B) ----
    if (rows2 && wv >= 4) {
      const int rl = wv - 4;
      float a2 = 0.f;
      if (p.resident) {
        int kb = 0;
        for (; kb + 256 <= HID; kb += 256) {
          const float4 a = ((const float4*)(HS + kb))[lane];
          uint32_t wb = *(const uint32_t*)(W2S + rl*HID + kb + (lane<<2));
          v2f lo = __builtin_amdgcn_cvt_pk_f32_fp8((int)wb, false);
          v2f hi = __builtin_amdgcn_cvt_pk_f32_fp8((int)wb, true);
          a2 = fmaf(lo.x, a.x, a2); a2 = fmaf(lo.y, a.y, a2);
          a2 = fmaf(hi.x, a.z, a2); a2 = fmaf(hi.y, a.w, a2);
        }
        if ((lane << 2) < HID - kb) {
          const float4 a = ((const float4*)(HS + kb))[lane];
          uint32_t wb = *(const uint32_t*)(W2S + rl*HID + kb + (lane<<2));
          v2f lo = __builtin_amdgcn_cvt_pk_f32_fp8((int)wb, false);
          v2f hi = __builtin_amdgcn_cvt_pk_f32_fp8((int)wb, true);
          a2 = fmaf(lo.x, a.x, a2); a2 = fmaf(lo.y, a.y, a2);
          a2 = fmaf(hi.x, a.z, a2); a2 = fmaf(hi.y, a.w, a2);
        }
        a2 *= INVWS;
      } else {
        for (int k = lane; k < HID; k += 64)
          a2 = fmaf(p.W2[(size_t)(r2s+rl)*HID + k], HS[k], a2);
      }
#pragma unroll
      for (int m = 32; m >= 1; m >>= 1) a2 += __shfl_xor(a2, m, 64);
      if (lane == 0) L2R[rl] = fmaxf(a2 + B2S[rl], 0.f);
    }
    __syncthreads();
    if (rows2 && tid < 4) {                      // publish 4 slot words
      float cp = L2R[0]*TS[tid*4+0] + L2R[1]*TS[tid*4+1]
               + L2R[2]*TS[tid*4+2] + L2R[3]*TS[tid*4+3];
      pub64(p.slt + (((size_t)par*NBLK + bid) << 3) + tid, want, cp);
    }

    // ---- E: ghh(t) for step t+1 (all waves; covers slot flight) ----
    ghh();

    // ---- F: slot reduce (waves 0-2: 192 packets) ----
    if (wv < 3) {
      int idx = (wv << 6) | lane;
      float v[4];
      poll_pkt<4>(p.slt + (((size_t)par*NBLK + idx) << 3), want, v, dead);
      float s0 = v[0], s1 = v[1], s2 = v[2], s3 = v[3];
#pragma unroll
      for (int m = 32; m >= 1; m >>= 1) {
        s0 += __shfl_xor(s0, m, 64); s1 += __shfl_xor(s1, m, 64);
        s2 += __shfl_xor(s2, m, 64); s3 += __shfl_xor(s3, m, 64);
      }
      if (lane == 0) {
        SLP[wv*4+0] = s0; SLP[wv*4+1] = s1; SLP[wv*4+2] = s2; SLP[wv*4+3] = s3;
      }
    }
    __syncthreads();

    // ---- W: wave-0 fused tail (posterior + full step-(t+1) prep) ----
    // All wave-synchronous: DS ops are in-order within a wave; cross-lane
    // data moves via shuffles. No block barrier until KN must be visible.
    if (wv == 0) {
      float xp = 0.f, dx = 0.f;
      if (lane < 4) {
        float c = SLP[lane] + SLP[4 + lane] + SLP[8 + lane];
        xp = myXpri + (c + myB4) * 1e-4f;
        if (bid == 0) p.out[(size_t)lane*TSEQ + t] = xp;
        dx = xp - myXpri;
      }
      if (t + 1 < TSEQ) {
        // broadcast xp, compute new prior on lanes 0-3
        float xp0 = __shfl(xp, 0), xp1 = __shfl(xp, 1),
              xp2 = __shfl(xp, 2), xp3 = __shfl(xp, 3);
        float xpri_new = 0.f;
        if (lane < 4)
          xpri_new = AS[lane*4+0]*xp0 + AS[lane*4+1]*xp1
                   + AS[lane*4+2]*xp2 + AS[lane*4+3]*xp3;
        if (lane < 4) myXpri = xpri_new;
        float xr0 = __shfl(xpri_new, 0), xr1 = __shfl(xpri_new, 1),
              xr2 = __shfl(xpri_new, 2), xr3 = __shfl(xpri_new, 3);
        // ||dx|| (lanes >=4 contribute 0)
        float qd = dx * dx;
#pragma unroll
        for (int m = 32; m >= 1; m >>= 1) qd += __shfl_xor(qd, m, 64);
        float n1 = fmaxf(sqrtf(qd), 1e-12f);
        // inn(t+1) on lanes 0-47
        float inn = 0.f;
        if (lane < 48) {
          float s = CS[lane*5 + 4] + CS[lane*5+0]*xr0 + CS[lane*5+1]*xr1
                  + CS[lane*5+2]*xr2 + CS[lane*5+3]*xr3;
          inn = p.y[(size_t)lane*TSEQ + (t+1)] - s;
          INNS[lane] = inn;
        }
        // ||inn||
        float qi = inn * inn;
#pragma unroll
        for (int m = 32; m >= 1; m >>= 1) qi += __shfl_xor(qi, m, 64);
        float n0 = fmaxf(sqrtf(qi), 1e-12f);
        // KN
        float knv;
        if (lane < 48)        knv = inn / n0;
        else if (lane < 52)   knv = __shfl(dx, lane - 48) / n1;
        else if (lane == 52)  knv = 1.0f;
        else                  knv = 0.0f;
        KN[lane] = knv;
        __builtin_amdgcn_wave_barrier();
        // B4(t+1) on lanes 0-3; TS(t+1) on lanes 8-23 (parallel in-wave)
        if (lane < 4) {
          float s = 0.f;
          for (int j = 0; j < 48; ++j) s += B3S[lane*48 + j] * INNS[j];
          myB4 = s;
        }
        if (rows2 && lane >= 8 && lane < 24) {
          int idx = lane - 8, rl = idx >> 2, i = idx & 3;
          float s = 0.f;
          for (int j = 0; j < 48; ++j) s += W3S[rl*192 + i*48 + j] * INNS[j];
          TS[i*4 + rl] = s;
        }
      }
    }
    __syncthreads();

    // ---- L: full l1(t+1) (all waves) ----
    if (t + 1 < TSEQ) {
      full_l1();
      __syncthreads();
    }
  }
}

// f32 -> fp8 e4m3 (x128), 4 elements per thread (W_ih full).
extern "C" __global__ void knet_cvt_fp8(const float* __restrict__ src,
                                        uint8_t* __restrict__ dst, long n4) {
  long stride = (long)gridDim.x * blockDim.x;
  for (long i = (long)blockIdx.x*blockDim.x + threadIdx.x; i < n4; i += stride) {
    float4 v = ((const float4*)src)[i];
    float a0 = fminf(fmaxf(v.x * 128.f, -448.f), 448.f);
    float a1 = fminf(fmaxf(v.y * 128.f, -448.f), 448.f);
    float a2 = fminf(fmaxf(v.z * 128.f, -448.f), 448.f);
    float a3 = fminf(fmaxf(v.w * 128.f, -448.f), 448.f);
    int pk = __builtin_amdgcn_cvt_pk_fp8_f32(a0, a1, 0, false);
    pk = __builtin_amdgcn_cvt_pk_fp8_f32(a2, a3, pk, true);
    ((uint32_t*)dst)[i] = (uint32_t)pk;
  }
}

// Build W1ext fp8: row r = [W1[r,0:52], b1[r], 0 x11] * 128, 64 B/row.
extern "C" __global__ void knet_build_w1e(const float* __restrict__ W1,
                                          const float* __restrict__ b1,
                                          uint8_t* __restrict__ dst) {
  int r = blockIdx.x * blockDim.x + threadIdx.x;
  if (r >= KIH) return;
  float v[64];
#pragma unroll 13
  for (int q = 0; q < 13; ++q) {
    float4 w = ((const float4*)(W1 + (size_t)r*52))[q];
    v[q*4+0] = w.x; v[q*4+1] = w.y; v[q*4+2] = w.z; v[q*4+3] = w.w;
  }
  v[52] = b1[r];
  for (int i = 53; i < 64; ++i) v[i] = 0.f;
  uint32_t out[16];
#pragma unroll 16
  for (int d = 0; d < 16; ++d) {
    float a0 = fminf(fmaxf(v[d*4+0] * 128.f, -448.f), 448.f);
    float a1 = fminf(fmaxf(v[d*4+1] * 128.f, -448.f), 448.f);
    float a2 = fminf(fmaxf(v[d*4+2] * 128.f, -448.f), 448.f);
    float a3 = fminf(fmaxf(v[d*4+3] * 128.f, -448.f), 448.f);
    int pk = __builtin_amdgcn_cvt_pk_fp8_f32(a0, a1, 0, false);
    pk = __builtin_amdgcn_cvt_pk_fp8_f32(a2, a3, pk, true);
    out[d] = (uint32_t)pk;
  }
  uint4* dp = (uint4*)(dst + (size_t)r*64);
#pragma unroll 4
  for (int q = 0; q < 4; ++q)
    dp[q] = make_uint4(out[q*4+0], out[q*4+1], out[q*4+2], out[q*4+3]);
}

extern "C" void kernel_launch(void* const* d_in, const int* in_sizes, int n_in,
                              void* d_out, int out_size, void* d_ws, size_t ws_size,
                              hipStream_t stream)
{
  if (ws_size < (size_t)WS_END) return;   // 29.3 MB (proven available)
  uint8_t* ws = (uint8_t*)d_ws;

  knet_cvt_fp8<<<2048, 256, 0, stream>>>((const float*)d_in[7], ws + WS_WIH8,
                                         (long)G3*KIH/4);
  knet_build_w1e<<<(KIH + 255)/256, 256, 0, stream>>>(
      (const float*)d_in[5], (const float*)d_in[6], ws + WS_W1E);
  // no memset needed: word tags are exact-match (t+1); 0xAA poison never matches

  int resident = 1;
  Offs o = mkoffs(resident);
  hipError_t e = hipFuncSetAttribute((const void*)knet_main,
                                     hipFuncAttributeMaxDynamicSharedMemorySize,
                                     o.total);
  if (e != hipSuccess) {
    resident = 0; o = mkoffs(resident);
    (void)hipFuncSetAttribute((const void*)knet_main,
                              hipFuncAttributeMaxDynamicSharedMemorySize, o.total);
  }

  Params p;
  p.A   = (const float*)d_in[0];  p.C   = (const float*)d_in[1];
  p.x0  = (const float*)d_in[2];  p.h0  = (const float*)d_in[3];
  p.y   = (const float*)d_in[4];
  p.W1  = (const float*)d_in[5];  p.b1  = (const float*)d_in[6];
  p.Wih = (const float*)d_in[7];  p.Whh = (const float*)d_in[8];
  p.bih = (const float*)d_in[9];  p.bhh = (const float*)d_in[10];
  p.W2  = (const float*)d_in[11]; p.b2  = (const float*)d_in[12];
  p.W3  = (const float*)d_in[13]; p.b3  = (const float*)d_in[14];
  p.wih8 = ws + WS_WIH8;
  p.w1e  = ws + WS_W1E;
  p.hbp  = (uint64_t*)(ws + WS_HBP);
  p.slt  = (uint64_t*)(ws + WS_SLT);
  p.out  = (float*)d_out;
  p.resident = resident;

  knet_main<<<NBLK, NTHR, (size_t)o.total, stream>>>(p);
}

// Round 5
// 8711.632 us; speedup vs baseline: 1.2218x; 1.1958x over previous
//
// KalmanNetNN persistent kernel, MI355X (gfx950).
// R13: exact R8 phase structure (the 8.29ms proven optimum) + myh +
//   bf16-packed h exchange.
// Post-mortems: R9 w1e-hoist spilled (+20ms); R10 gated poll +235us (settle
//   round-trip); R11 window-fill +2.1ms (barrier-gated fill > wait); R12
//   wave-0 fused tail +2.1ms (fewer barriers but longer serial chain -> the
//   232-block ring syncs to the slowest). Lesson: phase structure stays R8;
//   attack the exchange PAYLOAD instead.
// New: h packets pack 2 x bf16 per tagged 8B word -> 5 words (40B) instead of
//   10 (80B). Halves h-consume traffic (232 blocks x 232 pkts x rounds through
//   MALL) and halves loads per poll round. GRU recurrence stays f32 via myh;
//   only the broadcast copy is bf16 (~0.2% <= accepted fp8 weight error).
// Predicted: 7.6-8.2ms if consume-bound; ~8.3 flat if latency-bound.
//   VALUBusy ~30%, FETCH ~145MB, VGPR ~128.

#include <hip/hip_runtime.h>
#include <stdint.h>
#include <stddef.h>

typedef float v2f __attribute__((ext_vector_type(2)));

#define HID   2320
#define G3    6960
#define KIH   4160
#define KHH   2320
#define NBLK  232
#define NL2B  192              // blocks owning l2 rows (4 each = 768)
#define NTHR  512
#define UPB   10
#define TSEQ  512
#define KRES  1600
#define INVWS (1.0f/128.0f)
#define SPINCAP (1u<<17)

// ---------------- workspace layout (bytes) ----------------
#define WS_WIH8 0L            // 6960*4160 fp8
#define WS_W1E  28953600L     // 4160*64 fp8 W1ext (52 w + b1 + pad)
#define WS_HBP  29219840L     // 2 x 232 x 128B h packets (5 tagged bf16x2 words)
#define WS_SLT  29279232L     // 2 x 232 x 64B slot packets (4 tagged words)
#define WS_END  29308928L

struct Offs {
  int l1s, hs, wih, whh, w2s, w3s, cs, as_, b3s, bih, bhh, b2s, gis, ghs,
      ts, inn, kn, dxs, xpri, xpo, b4, nrm, l2r, slp;
  int total;
};

__host__ __device__ inline Offs mkoffs(int res) {
  Offs o; int p = 0;
#define ALLOC(name, bytes) { p = (p + 15) & ~15; o.name = p; p += (bytes); }
  ALLOC(l1s, KIH*4) ALLOC(hs, HID*4)
  ALLOC(wih, res ? 30*KRES : 16) ALLOC(whh, res ? 30*KHH : 16)
  ALLOC(w2s, res ? 4*HID : 16)
  ALLOC(w3s, 16*48*4) ALLOC(cs, 240*4) ALLOC(as_, 64) ALLOC(b3s, 192*4)
  ALLOC(bih, 120) ALLOC(bhh, 120) ALLOC(b2s, 16)
  ALLOC(gis, 120) ALLOC(ghs, 120)
  ALLOC(ts, 64) ALLOC(inn, 192) ALLOC(kn, 256)
  ALLOC(dxs, 16) ALLOC(xpri, 16) ALLOC(xpo, 16) ALLOC(b4, 16) ALLOC(nrm, 16)
  ALLOC(l2r, 16) ALLOC(slp, 64)
#undef ALLOC
  o.total = (p + 63) & ~63;
  return o;
}

struct Params {
  const float *A, *C, *x0, *h0, *y, *W1, *b1, *Wih, *Whh, *bih, *bhh, *W2, *b2, *W3, *b3;
  const uint8_t *wih8, *w1e;
  uint64_t *hbp, *slt;
  float *out;
  int resident;
};

__device__ __forceinline__ uint8_t f2fp8(float v) {
  v = fminf(fmaxf(v * 128.f, -448.f), 448.f);
  int pk = __builtin_amdgcn_cvt_pk_fp8_f32(v, v, 0, false);
  return (uint8_t)(pk & 0xff);
}

// f32 -> bf16 bits (round-to-nearest-even)
__device__ __forceinline__ uint32_t f2bf(float x) {
  uint32_t b = __float_as_uint(x);
  return (b + 0x7fffu + ((b >> 16) & 1u)) >> 16;
}

// fire-and-forget tagged publish: one self-validating 8B word (f32 payload).
__device__ __forceinline__ void pub64(uint64_t* a, uint32_t tag, float v) {
  uint64_t w = ((uint64_t)tag << 32) | (uint64_t)__float_as_uint(v);
  __hip_atomic_store(a, w, __ATOMIC_RELAXED, __HIP_MEMORY_SCOPE_AGENT);
}
// raw-u32 payload variant (bf16x2 packed)
__device__ __forceinline__ void pub64u(uint64_t* a, uint32_t tag, uint32_t pay) {
  uint64_t w = ((uint64_t)tag << 32) | (uint64_t)pay;
  __hip_atomic_store(a, w, __ATOMIC_RELAXED, __HIP_MEMORY_SCOPE_AGENT);
}

// full-packet poll (R8 form): all N tagged words each round, hot 8 rounds.
template<int N>
__device__ __forceinline__ void poll_pkt(const uint64_t* base, uint32_t want,
                                         float* out, bool& dead) {
  uint64_t v[N];
  uint32_t spins = 0;
  for (;;) {
    bool ok = true;
#pragma unroll
    for (int k = 0; k < N; ++k)
      v[k] = __hip_atomic_load(base + k, __ATOMIC_RELAXED, __HIP_MEMORY_SCOPE_AGENT);
#pragma unroll
    for (int k = 0; k < N; ++k) ok &= ((uint32_t)(v[k] >> 32) == want);
    if (ok || dead) break;
    ++spins;
    if (spins > 8) __builtin_amdgcn_s_sleep(2);
    if (spins > SPINCAP) dead = true;
  }
#pragma unroll
  for (int k = 0; k < N; ++k) out[k] = __uint_as_float((uint32_t)v[k]);
}

// full-packet poll, u32 payloads.
template<int N>
__device__ __forceinline__ void poll_pktu(const uint64_t* base, uint32_t want,
                                          uint32_t* out, bool& dead) {
  uint64_t v[N];
  uint32_t spins = 0;
  for (;;) {
    bool ok = true;
#pragma unroll
    for (int k = 0; k < N; ++k)
      v[k] = __hip_atomic_load(base + k, __ATOMIC_RELAXED, __HIP_MEMORY_SCOPE_AGENT);
#pragma unroll
    for (int k = 0; k < N; ++k) ok &= ((uint32_t)(v[k] >> 32) == want);
    if (ok || dead) break;
    ++spins;
    if (spins > 8) __builtin_amdgcn_s_sleep(2);
    if (spins > SPINCAP) dead = true;
  }
#pragma unroll
  for (int k = 0; k < N; ++k) out[k] = (uint32_t)v[k];
}

// 16-wide fp8 dot fragment: acc += dot(fp8x16(w), [a0 a1 a2 a3])
__device__ __forceinline__ float fma16(uint4 w, float4 a0, float4 a1,
                                       float4 a2, float4 a3, float acc) {
  v2f l0 = __builtin_amdgcn_cvt_pk_f32_fp8((int)w.x, false);
  v2f h0 = __builtin_amdgcn_cvt_pk_f32_fp8((int)w.x, true);
  v2f l1 = __builtin_amdgcn_cvt_pk_f32_fp8((int)w.y, false);
  v2f h1 = __builtin_amdgcn_cvt_pk_f32_fp8((int)w.y, true);
  v2f l2 = __builtin_amdgcn_cvt_pk_f32_fp8((int)w.z, false);
  v2f h2 = __builtin_amdgcn_cvt_pk_f32_fp8((int)w.z, true);
  v2f l3 = __builtin_amdgcn_cvt_pk_f32_fp8((int)w.w, false);
  v2f h3 = __builtin_amdgcn_cvt_pk_f32_fp8((int)w.w, true);
  acc = fmaf(l0.x,a0.x,acc); acc = fmaf(l0.y,a0.y,acc);
  acc = fmaf(h0.x,a0.z,acc); acc = fmaf(h0.y,a0.w,acc);
  acc = fmaf(l1.x,a1.x,acc); acc = fmaf(l1.y,a1.y,acc);
  acc = fmaf(h1.x,a1.z,acc); acc = fmaf(h1.y,a1.w,acc);
  acc = fmaf(l2.x,a2.x,acc); acc = fmaf(l2.y,a2.y,acc);
  acc = fmaf(h2.x,a2.z,acc); acc = fmaf(h2.y,a2.w,acc);
  acc = fmaf(l3.x,a3.x,acc); acc = fmaf(l3.y,a3.y,acc);
  acc = fmaf(h3.x,a3.z,acc); acc = fmaf(h3.y,a3.w,acc);
  return acc;
}

// fp8 row-dot, LDS weights, <=4 rows/wave, lanes split K.
__device__ __forceinline__ void dot8_lds(
    const float* __restrict__ acts, const uint8_t* __restrict__ w, int stride,
    int K, const int* lrows, int nr, int lane, float acc[4])
{
  int kb = 0;
  for (; kb + 256 <= K; kb += 256) {
    const float4 a = ((const float4*)(acts + kb))[lane];
#pragma unroll
    for (int j = 0; j < 4; ++j) if (j < nr) {
      uint32_t wb = *(const uint32_t*)(w + (size_t)lrows[j]*stride + kb + (lane<<2));
      v2f lo = __builtin_amdgcn_cvt_pk_f32_fp8((int)wb, false);
      v2f hi = __builtin_amdgcn_cvt_pk_f32_fp8((int)wb, true);
      acc[j] = fmaf(lo.x, a.x, acc[j]); acc[j] = fmaf(lo.y, a.y, acc[j]);
      acc[j] = fmaf(hi.x, a.z, acc[j]); acc[j] = fmaf(hi.y, a.w, acc[j]);
    }
  }
  int rem = K - kb;
  if ((lane << 2) < rem) {
    const float4 a = ((const float4*)(acts + kb))[lane];
#pragma unroll
    for (int j = 0; j < 4; ++j) if (j < nr) {
      uint32_t wb = *(const uint32_t*)(w + (size_t)lrows[j]*stride + kb + (lane<<2));
      v2f lo = __builtin_amdgcn_cvt_pk_f32_fp8((int)wb, false);
      v2f hi = __builtin_amdgcn_cvt_pk_f32_fp8((int)wb, true);
      acc[j] = fmaf(lo.x, a.x, acc[j]); acc[j] = fmaf(lo.y, a.y, acc[j]);
      acc[j] = fmaf(hi.x, a.z, acc[j]); acc[j] = fmaf(hi.y, a.w, acc[j]);
    }
  }
}

// fp8 row-dot, global weights, cols [K0,K).
__device__ __forceinline__ void dot8_glb(
    const float* __restrict__ acts, const uint8_t* __restrict__ gw, int gstride,
    int K0, int K, const int* grows, int nr, int lane, float acc[4])
{
  int kb = K0;
  for (; kb + 512 <= K; kb += 512) {
    const float4 a0 = ((const float4*)(acts + kb))[lane*2];
    const float4 a1 = ((const float4*)(acts + kb))[lane*2 + 1];
#pragma unroll
    for (int j = 0; j < 4; ++j) if (j < nr) {
      uint2 wb = *(const uint2*)(gw + (size_t)grows[j]*gstride + kb + (lane<<3));
      v2f l0 = __builtin_amdgcn_cvt_pk_f32_fp8((int)wb.x, false);
      v2f h0 = __builtin_amdgcn_cvt_pk_f32_fp8((int)wb.x, true);
      v2f l1 = __builtin_amdgcn_cvt_pk_f32_fp8((int)wb.y, false);
      v2f h1 = __builtin_amdgcn_cvt_pk_f32_fp8((int)wb.y, true);
      acc[j] = fmaf(l0.x, a0.x, acc[j]); acc[j] = fmaf(l0.y, a0.y, acc[j]);
      acc[j] = fmaf(h0.x, a0.z, acc[j]); acc[j] = fmaf(h0.y, a0.w, acc[j]);
      acc[j] = fmaf(l1.x, a1.x, acc[j]); acc[j] = fmaf(l1.y, a1.y, acc[j]);
      acc[j] = fmaf(h1.x, a1.z, acc[j]); acc[j] = fmaf(h1.y, a1.w, acc[j]);
    }
  }
  for (int e = kb + lane; e < K; e += 64) {
    float a = acts[e];
#pragma unroll
    for (int j = 0; j < 4; ++j) if (j < nr) {
      v2f lo = __builtin_amdgcn_cvt_pk_f32_fp8(
          (int)(uint32_t)gw[(size_t)grows[j]*gstride + e], false);
      acc[j] = fmaf(lo.x, a, acc[j]);
    }
  }
}

// f32 row-dot, global weights (fallback ghh).
__device__ __forceinline__ void dotf_glb(
    const float* __restrict__ acts, const float* __restrict__ gw, int gstride,
    int K, const int* grows, int nr, int lane, float acc[4])
{
  for (int k = lane; k < K; k += 64) {
    float a = acts[k];
#pragma unroll
    for (int j = 0; j < 4; ++j) if (j < nr)
      acc[j] = fmaf(gw[(size_t)grows[j]*gstride + k], a, acc[j]);
  }
}

extern "C" __global__ void __launch_bounds__(NTHR, 2) knet_main(Params p)
{
  extern __shared__ char smem[];
  const Offs o = mkoffs(p.resident);
  float*   L1S  = (float*)(smem + o.l1s);
  float*   HS   = (float*)(smem + o.hs);
  uint8_t* WIHR = (uint8_t*)(smem + o.wih);
  uint8_t* WHHR = (uint8_t*)(smem + o.whh);
  uint8_t* W2S  = (uint8_t*)(smem + o.w2s);
  float*   W3S  = (float*)(smem + o.w3s);
  float*   CS   = (float*)(smem + o.cs);
  float*   AS   = (float*)(smem + o.as_);
  float*   B3S  = (float*)(smem + o.b3s);
  float*   BIH  = (float*)(smem + o.bih);
  float*   BHH  = (float*)(smem + o.bhh);
  float*   B2S  = (float*)(smem + o.b2s);
  float*   GIS  = (float*)(smem + o.gis);
  float*   GHS  = (float*)(smem + o.ghs);
  float*   TS   = (float*)(smem + o.ts);
  float*   INNS = (float*)(smem + o.inn);
  float*   KN   = (float*)(smem + o.kn);
  float*   DXS  = (float*)(smem + o.dxs);
  float*   XPRI = (float*)(smem + o.xpri);
  float*   XPO  = (float*)(smem + o.xpo);
  float*   B4   = (float*)(smem + o.b4);
  float*   NRM  = (float*)(smem + o.nrm);
  float*   L2R  = (float*)(smem + o.l2r);
  float*   SLP  = (float*)(smem + o.slp);

  const int tid  = (int)threadIdx.x;
  const int bid  = (int)blockIdx.x;
  const int lane = tid & 63;
  const int wv   = tid >> 6;
  const int rows2 = (bid < NL2B) ? 4 : 0;              // uniform l2 ownership
  const int r2s   = bid * 4;
  bool dead = false;

  int lrows[4] = {0,0,0,0}, grows[4] = {0,0,0,0};
  int nr = 0;
#pragma unroll
  for (int j = 0; j < 4; ++j) {
    int row = wv + 8*j;
    if (row < 30) { int u = row/3, g = row - 3*u;
      lrows[nr] = row; grows[nr] = g*HID + bid*UPB + u; ++nr; }
  }

  // ---------------- one-time staging ----------------
  for (int i = tid; i < rows2*192; i += NTHR) { int rl = i/192, rem = i - rl*192;
    W3S[i] = p.W3[(size_t)rem*768 + (r2s + rl)]; }
  for (int i = tid; i < 240; i += NTHR) CS[i] = p.C[i];
  if (tid < 16) AS[tid] = p.A[tid];
  for (int i = tid; i < 192; i += NTHR) B3S[i] = p.b3[i];
  if (tid < rows2) B2S[tid] = p.b2[r2s + tid];
  if (tid < 30) {
    int u = tid/3, g = tid - 3*u, ug = bid*UPB + u;
    BIH[tid] = p.bih[g*HID + ug];
    BHH[tid] = p.bhh[g*HID + ug];
  }
  for (int i = tid; i < HID; i += NTHR) HS[i] = p.h0[i];
  // own-unit hidden state held in a register (tid < UPB only).
  float myh = (tid < UPB) ? p.h0[(size_t)bid*UPB + tid] : 0.f;
  if (p.resident) {
    const int kd = KRES >> 2;                   // W_ih resident cols from fp8 ws
    uint32_t* W32 = (uint32_t*)WIHR;
    for (int i = tid; i < 30*kd; i += NTHR) {
      int row = i / kd, c = i - row*kd;
      int u = row/3, g = row - 3*u, gr = g*HID + bid*UPB + u;
      W32[i] = ((const uint32_t*)p.wih8)[(size_t)gr*(KIH/4) + c];
    }
    for (int i = tid; i < 30*KHH; i += NTHR) {  // W_hh rows f32->fp8
      int row = i / KHH, k = i - row*KHH;
      int u = row/3, g = row - 3*u, gr = g*HID + bid*UPB + u;
      WHHR[i] = f2fp8(p.Whh[(size_t)gr*KHH + k]);
    }
    for (int i = tid; i < rows2*HID; i += NTHR) { // W2 slice f32->fp8
      int rl = i / HID, k = i - rl*HID;
      W2S[i] = f2fp8(p.W2[(size_t)(r2s+rl)*HID + k]);
    }
  }
  // streamed W_ih cols [KRES,4160) hoisted into VGPRs (constant across steps)
  uint2 pf[4][5];
#pragma unroll
  for (int j = 0; j < 4; ++j)
#pragma unroll
    for (int i = 0; i < 5; ++i) pf[j][i] = make_uint2(0u, 0u);
#pragma unroll
  for (int j = 0; j < 4; ++j) if (j < nr)
#pragma unroll
    for (int i = 0; i < 5; ++i)
      pf[j][i] = *(const uint2*)(p.wih8 + (size_t)grows[j]*KIH + KRES + i*512 + (lane<<3));
  __syncthreads();

  // small chain producing step-`ycol` inputs: INNS, KN, B4, TS, full l1.
  auto small_chain = [&](int ycol) {
    if (tid < 48) {
      float s = CS[tid*5 + 4];
#pragma unroll
      for (int k = 0; k < 4; ++k) s += CS[tid*5 + k] * XPRI[k];
      INNS[tid] = p.y[(size_t)tid*TSEQ + ycol] - s;
    }
    __syncthreads();
    if (wv == 0) {                               // parallel ||inn||
      float q = (lane < 48) ? INNS[lane]*INNS[lane] : 0.f;
#pragma unroll
      for (int m = 32; m >= 1; m >>= 1) q += __shfl_xor(q, m, 64);
      if (lane == 0) NRM[0] = fmaxf(sqrtf(q), 1e-12f);
    } else if (wv == 1) {                        // parallel ||dx||
      float q = (lane < 4) ? DXS[lane]*DXS[lane] : 0.f;
#pragma unroll
      for (int m = 32; m >= 1; m >>= 1) q += __shfl_xor(q, m, 64);
      if (lane == 0) NRM[1] = fmaxf(sqrtf(q), 1e-12f);
    }
    __syncthreads();
    if (tid < 48) KN[tid] = INNS[tid] / NRM[0];
    else if (tid < 52) KN[tid] = DXS[tid-48] / NRM[1];
    else if (tid == 52) KN[tid] = 1.0f;
    else if (tid < 64) KN[tid] = 0.0f;
    else if (tid < 68) {
      int i = tid - 64; float s = 0;
      for (int j = 0; j < 48; ++j) s += B3S[i*48 + j] * INNS[j];
      B4[i] = s;
    }
    if (tid >= 128 && tid < 128 + rows2*4) {
      int idx = tid - 128, rl = idx >> 2, i = idx & 3;
      float s = 0;
      for (int j = 0; j < 48; ++j) s += W3S[rl*192 + i*48 + j] * INNS[j];
      TS[i*4 + rl] = s;
    }
    __syncthreads();
    {                                            // redundant full l1
      float4 kn[16];
#pragma unroll
      for (int c = 0; c < 16; ++c) kn[c] = ((const float4*)KN)[c];
      for (int r = tid; r < KIH; r += NTHR) {
        const uint4* wp = (const uint4*)(p.w1e + (size_t)r*64);
        float acc = 0.f;
#pragma unroll
        for (int q = 0; q < 4; ++q) {
          uint4 w = wp[q];
          acc = fma16(w, kn[q*4+0], kn[q*4+1], kn[q*4+2], kn[q*4+3], acc);
        }
        L1S[r] = fmaxf(acc * INVWS, 0.f);
      }
    }
    __syncthreads();
  };

  auto ghh = [&]() {                             // W_hh @ HS -> GHS
    float acc[4] = {0,0,0,0};
    if (p.resident) dot8_lds(HS, WHHR, KHH, KHH, lrows, nr, lane, acc);
    else            dotf_glb(HS, p.Whh, KHH, KHH, grows, nr, lane, acc);
#pragma unroll
    for (int m = 32; m >= 1; m >>= 1)
#pragma unroll
      for (int j = 0; j < 4; ++j) acc[j] += __shfl_xor(acc[j], m, 64);
    if (lane == 0)
#pragma unroll
      for (int j = 0; j < 4; ++j) if (j < nr) GHS[lrows[j]] = acc[j];
  };

  // ---------------- pre-loop ----------------
  if (tid < 4) { XPO[tid] = p.x0[tid]; DXS[tid] = 0.f; }
  __syncthreads();
  if (tid < 4) {
    float s = 0;
#pragma unroll
    for (int j = 0; j < 4; ++j) s += AS[tid*4 + j] * XPO[j];
    XPRI[tid] = s;
  }
  __syncthreads();
  small_chain(0);
  ghh();
  __syncthreads();

  // ---------------- main sequence ----------------
  for (int t = 0; t < TSEQ; ++t) {
    const int par = t & 1;
    const uint32_t want = (uint32_t)(t + 1);

    // ---- A: gate-dot gi = W_ih @ l1(t) ----
    {
      float acc[4] = {0,0,0,0};
      if (p.resident) dot8_lds(L1S, WIHR, KRES, KRES, lrows, nr, lane, acc);
      else            dot8_glb(L1S, p.wih8, KIH, 0, KRES, grows, nr, lane, acc);
#pragma unroll
      for (int i = 0; i < 5; ++i) {              // VGPR-held streamed cols
        const float4 a0 = ((const float4*)(L1S + KRES + i*512))[lane*2];
        const float4 a1 = ((const float4*)(L1S + KRES + i*512))[lane*2 + 1];
#pragma unroll
        for (int j = 0; j < 4; ++j) if (j < nr) {
          uint2 w = pf[j][i];
          v2f l0 = __builtin_amdgcn_cvt_pk_f32_fp8((int)w.x, false);
          v2f h0 = __builtin_amdgcn_cvt_pk_f32_fp8((int)w.x, true);
          v2f l1v = __builtin_amdgcn_cvt_pk_f32_fp8((int)w.y, false);
          v2f h1 = __builtin_amdgcn_cvt_pk_f32_fp8((int)w.y, true);
          acc[j] = fmaf(l0.x, a0.x, acc[j]); acc[j] = fmaf(l0.y, a0.y, acc[j]);
          acc[j] = fmaf(h0.x, a0.z, acc[j]); acc[j] = fmaf(h0.y, a0.w, acc[j]);
          acc[j] = fmaf(l1v.x, a1.x, acc[j]); acc[j] = fmaf(l1v.y, a1.y, acc[j]);
          acc[j] = fmaf(h1.x, a1.z, acc[j]); acc[j] = fmaf(h1.y, a1.w, acc[j]);
        }
      }
#pragma unroll
      for (int m = 32; m >= 1; m >>= 1)
#pragma unroll
        for (int j = 0; j < 4; ++j) acc[j] += __shfl_xor(acc[j], m, 64);
      if (lane == 0)
#pragma unroll
        for (int j = 0; j < 4; ++j) if (j < nr) GIS[lrows[j]] = acc[j];
    }
    __syncthreads();

    // ---- B: h(t) + fire-and-forget bf16x2 tagged publish ----
    // B reads only GIS/GHS/BIH/BHH + register myh: no barrier needed before
    // C overwrites HS.
    float hnew = 0.f;
    if (tid < UPB) {
      int r0 = tid*3;
      float gi0 = GIS[r0+0]*INVWS + BIH[r0+0], gh0 = GHS[r0+0]*INVWS + BHH[r0+0];
      float gi1 = GIS[r0+1]*INVWS + BIH[r0+1], gh1 = GHS[r0+1]*INVWS + BHH[r0+1];
      float gi2 = GIS[r0+2]*INVWS + BIH[r0+2], gh2 = GHS[r0+2]*INVWS + BHH[r0+2];
      float rg = 1.f/(1.f + expf(-(gi0+gh0)));
      float zg = 1.f/(1.f + expf(-(gi1+gh1)));
      float ng = tanhf(gi2 + rg*gh2);
      hnew = (1.f - zg)*ng + zg*myh;
      myh = hnew;
    }
    if (wv == 0) {                               // pack pairs via shuffle
      float ha = __shfl(hnew, lane*2);
      float hb = __shfl(hnew, lane*2 + 1);
      if (lane < 5) {
        uint32_t pay = f2bf(ha) | (f2bf(hb) << 16);
        pub64u(p.hbp + (((size_t)par*NBLK + bid) << 4) + lane, want, pay);
      }
    }

    // ---- C: h broadcast consume -> HS (waves 0-3), bf16x2 unpack ----
    if (wv < 4) {
      int idx = (wv << 6) | lane;
      if (idx < NBLK) {
        uint32_t v[5];
        poll_pktu<5>(p.hbp + (((size_t)par*NBLK + idx) << 4), want, v, dead);
#pragma unroll
        for (int k = 0; k < 5; ++k) {
          HS[idx*10 + 2*k]     = __uint_as_float(v[k] << 16);
          HS[idx*10 + 2*k + 1] = __uint_as_float(v[k] & 0xffff0000u);
        }
      }
    }
    __syncthreads();

    // ---- D: l2 rows, one per wave on waves 4-7 (blocks < NL2B) ----
    if (rows2 && wv >= 4) {
      const int rl = wv - 4;
      float a2 = 0.f;
      if (p.resident) {
        int kb = 0;
        for (; kb + 256 <= HID; kb += 256) {
          const float4 a = ((const float4*)(HS + kb))[lane];
          uint32_t wb = *(const uint32_t*)(W2S + rl*HID + kb + (lane<<2));
          v2f lo = __builtin_amdgcn_cvt_pk_f32_fp8((int)wb, false);
          v2f hi = __builtin_amdgcn_cvt_pk_f32_fp8((int)wb, true);
          a2 = fmaf(lo.x, a.x, a2); a2 = fmaf(lo.y, a.y, a2);
          a2 = fmaf(hi.x, a.z, a2); a2 = fmaf(hi.y, a.w, a2);
        }
        if ((lane << 2) < HID - kb) {
          const float4 a = ((const float4*)(HS + kb))[lane];
          uint32_t wb = *(const uint32_t*)(W2S + rl*HID + kb + (lane<<2));
          v2f lo = __builtin_amdgcn_cvt_pk_f32_fp8((int)wb, false);
          v2f hi = __builtin_amdgcn_cvt_pk_f32_fp8((int)wb, true);
          a2 = fmaf(lo.x, a.x, a2); a2 = fmaf(lo.y, a.y, a2);
          a2 = fmaf(hi.x, a.z, a2); a2 = fmaf(hi.y, a.w, a2);
        }
        a2 *= INVWS;
      } else {
        for (int k = lane; k < HID; k += 64)
          a2 = fmaf(p.W2[(size_t)(r2s+rl)*HID + k], HS[k], a2);
      }
#pragma unroll
      for (int m = 32; m >= 1; m >>= 1) a2 += __shfl_xor(a2, m, 64);
      if (lane == 0) L2R[rl] = fmaxf(a2 + B2S[rl], 0.f);
    }
    __syncthreads();
    if (rows2 && tid < 4) {                      // publish 4 slot words
      float cp = L2R[0]*TS[tid*4+0] + L2R[1]*TS[tid*4+1]
               + L2R[2]*TS[tid*4+2] + L2R[3]*TS[tid*4+3];
      pub64(p.slt + (((size_t)par*NBLK + bid) << 3) + tid, want, cp);
    }

    // ---- E: ghh(t) for step t+1 (all waves; covers slot flight) ----
    ghh();

    // ---- F: slot reduce (waves 0-2: 192 packets) ----
    if (wv < 3) {
      int idx = (wv << 6) | lane;
      float v[4];
      poll_pkt<4>(p.slt + (((size_t)par*NBLK + idx) << 3), want, v, dead);
      float s0 = v[0], s1 = v[1], s2 = v[2], s3 = v[3];
#pragma unroll
      for (int m = 32; m >= 1; m >>= 1) {
        s0 += __shfl_xor(s0, m, 64); s1 += __shfl_xor(s1, m, 64);
        s2 += __shfl_xor(s2, m, 64); s3 += __shfl_xor(s3, m, 64);
      }
      if (lane == 0) {
        SLP[wv*4+0] = s0; SLP[wv*4+1] = s1; SLP[wv*4+2] = s2; SLP[wv*4+3] = s3;
      }
    }
    __syncthreads();

    // ---- G: posterior + next-step chain ----
    if (tid < 4) {
      float c = SLP[tid] + SLP[4 + tid] + SLP[8 + tid];
      float xp = XPRI[tid] + (c + B4[tid]) * 1e-4f;
      XPO[tid] = xp;
      if (bid == 0) p.out[(size_t)tid*TSEQ + t] = xp;
    }
    __syncthreads();
    if (t + 1 < TSEQ) {
      if (tid < 4) {
        float xo = XPO[tid];
        DXS[tid] = xo - XPRI[tid];
        float s = 0;
#pragma unroll
        for (int j = 0; j < 4; ++j) s += AS[tid*4 + j] * XPO[j];
        XPRI[tid] = s;
      }
      __syncthreads();
      small_chain(t + 1);                        // ends with syncthreads
    }
  }
}

// f32 -> fp8 e4m3 (x128), 4 elements per thread (W_ih full).
extern "C" __global__ void knet_cvt_fp8(const float* __restrict__ src,
                                        uint8_t* __restrict__ dst, long n4) {
  long stride = (long)gridDim.x * blockDim.x;
  for (long i = (long)blockIdx.x*blockDim.x + threadIdx.x; i < n4; i += stride) {
    float4 v = ((const float4*)src)[i];
    float a0 = fminf(fmaxf(v.x * 128.f, -448.f), 448.f);
    float a1 = fminf(fmaxf(v.y * 128.f, -448.f), 448.f);
    float a2 = fminf(fmaxf(v.z * 128.f, -448.f), 448.f);
    float a3 = fminf(fmaxf(v.w * 128.f, -448.f), 448.f);
    int pk = __builtin_amdgcn_cvt_pk_fp8_f32(a0, a1, 0, false);
    pk = __builtin_amdgcn_cvt_pk_fp8_f32(a2, a3, pk, true);
    ((uint32_t*)dst)[i] = (uint32_t)pk;
  }
}

// Build W1ext fp8: row r = [W1[r,0:52], b1[r], 0 x11] * 128, 64 B/row.
extern "C" __global__ void knet_build_w1e(const float* __restrict__ W1,
                                          const float* __restrict__ b1,
                                          uint8_t* __restrict__ dst) {
  int r = blockIdx.x * blockDim.x + threadIdx.x;
  if (r >= KIH) return;
  float v[64];
#pragma unroll 13
  for (int q = 0; q < 13; ++q) {
    float4 w = ((const float4*)(W1 + (size_t)r*52))[q];
    v[q*4+0] = w.x; v[q*4+1] = w.y; v[q*4+2] = w.z; v[q*4+3] = w.w;
  }
  v[52] = b1[r];
  for (int i = 53; i < 64; ++i) v[i] = 0.f;
  uint32_t out[16];
#pragma unroll 16
  for (int d = 0; d < 16; ++d) {
    float a0 = fminf(fmaxf(v[d*4+0] * 128.f, -448.f), 448.f);
    float a1 = fminf(fmaxf(v[d*4+1] * 128.f, -448.f), 448.f);
    float a2 = fminf(fmaxf(v[d*4+2] * 128.f, -448.f), 448.f);
    float a3 = fminf(fmaxf(v[d*4+3] * 128.f, -448.f), 448.f);
    int pk = __builtin_amdgcn_cvt_pk_fp8_f32(a0, a1, 0, false);
    pk = __builtin_amdgcn_cvt_pk_fp8_f32(a2, a3, pk, true);
    out[d] = (uint32_t)pk;
  }
  uint4* dp = (uint4*)(dst + (size_t)r*64);
#pragma unroll 4
  for (int q = 0; q < 4; ++q)
    dp[q] = make_uint4(out[q*4+0], out[q*4+1], out[q*4+2], out[q*4+3]);
}

extern "C" void kernel_launch(void* const* d_in, const int* in_sizes, int n_in,
                              void* d_out, int out_size, void* d_ws, size_t ws_size,
                              hipStream_t stream)
{
  if (ws_size < (size_t)WS_END) return;   // 29.3 MB (proven available)
  uint8_t* ws = (uint8_t*)d_ws;

  knet_cvt_fp8<<<2048, 256, 0, stream>>>((const float*)d_in[7], ws + WS_WIH8,
                                         (long)G3*KIH/4);
  knet_build_w1e<<<(KIH + 255)/256, 256, 0, stream>>>(
      (const float*)d_in[5], (const float*)d_in[6], ws + WS_W1E);
  // no memset needed: word tags are exact-match (t+1); 0xAA poison never matches

  int resident = 1;
  Offs o = mkoffs(resident);
  hipError_t e = hipFuncSetAttribute((const void*)knet_main,
                                     hipFuncAttributeMaxDynamicSharedMemorySize,
                                     o.total);
  if (e != hipSuccess) {
    resident = 0; o = mkoffs(resident);
    (void)hipFuncSetAttribute((const void*)knet_main,
                              hipFuncAttributeMaxDynamicSharedMemorySize, o.total);
  }

  Params p;
  p.A   = (const float*)d_in[0];  p.C   = (const float*)d_in[1];
  p.x0  = (const float*)d_in[2];  p.h0  = (const float*)d_in[3];
  p.y   = (const float*)d_in[4];
  p.W1  = (const float*)d_in[5];  p.b1  = (const float*)d_in[6];
  p.Wih = (const float*)d_in[7];  p.Whh = (const float*)d_in[8];
  p.bih = (const float*)d_in[9];  p.bhh = (const float*)d_in[10];
  p.W2  = (const float*)d_in[11]; p.b2  = (const float*)d_in[12];
  p.W3  = (const float*)d_in[13]; p.b3  = (const float*)d_in[14];
  p.wih8 = ws + WS_WIH8;
  p.w1e  = ws + WS_W1E;
  p.hbp  = (uint64_t*)(ws + WS_HBP);
  p.slt  = (uint64_t*)(ws + WS_SLT);
  p.out  = (float*)d_out;
  p.resident = resident;

  knet_main<<<NBLK, NTHR, (size_t)o.total, stream>>>(p);
}

// Round 7
// 8262.510 us; speedup vs baseline: 1.2882x; 1.0544x over previous
//
// KalmanNetNN persistent kernel, MI355X (gfx950).
// R14 (resubmit — prior round failed with GPUAcquisitionTimeout, never ran).
// Full return to R8 semantics + ONE minimal change (poll hot window).
// Ledger of failed deviations from R8 (8290us):
//   R9  w1e VGPR hoist      -> spilled to scratch, +20ms
//   R10 gated poll (+myh)   -> +315us
//   R11 window-fill l1a     -> barrier-gated fill > wait, +2.3ms
//   R12 wave-0 fused tail   -> longer serial chain, +2.1ms
//   R13 bf16 h-packets(+myh)-> +413us  => h-exchange is LATENCY-bound
// Confound resolved: R10/R13's common element was DROPPING the post-B barrier
//   (myh). Without it, waves 1-3 enter the C-poll before the block publishes,
//   burn the 8-round hot window on stale reads, and fall into s_sleep(2)
//   quantization exactly when remote packets land. The barrier PACES poll
//   entry. Restored here; myh kept (with barrier it's bit-identical to R8,
//   one fewer LDS read).
// One-variable change vs R8: poll hot window 8 -> 32 rounds before first
//   s_sleep(2). If a poll legitimately exceeds 8 miss-rounds (entry skew),
//   R8 pays 128-cycle sleep quanta on the critical packet; spin traffic is
//   proven cheap (R9/R13), so widening is low-risk.
// Predicted: 8.20-8.35ms; WRITE ~26.7MB, FETCH ~145MB, VALU ~30%, VGPR 128,
//   absmax 2.68e8. >8.4ms => revert hot window next.

#include <hip/hip_runtime.h>
#include <stdint.h>
#include <stddef.h>

typedef float v2f __attribute__((ext_vector_type(2)));

#define HID   2320
#define G3    6960
#define KIH   4160
#define KHH   2320
#define NBLK  232
#define NL2B  192              // blocks owning l2 rows (4 each = 768)
#define NTHR  512
#define UPB   10
#define TSEQ  512
#define KRES  1600
#define INVWS (1.0f/128.0f)
#define SPINHOT 32u
#define SPINCAP (1u<<17)

// ---------------- workspace layout (bytes) ----------------
#define WS_WIH8 0L            // 6960*4160 fp8
#define WS_W1E  28953600L     // 4160*64 fp8 W1ext (52 w + b1 + pad)
#define WS_HBP  29219840L     // 2 x 232 x 128B h packets (10 tagged words)
#define WS_SLT  29279232L     // 2 x 232 x 64B slot packets (4 tagged words)
#define WS_END  29308928L

struct Offs {
  int l1s, hs, wih, whh, w2s, w3s, cs, as_, b3s, bih, bhh, b2s, gis, ghs,
      ts, inn, kn, dxs, xpri, xpo, b4, nrm, l2r, slp;
  int total;
};

__host__ __device__ inline Offs mkoffs(int res) {
  Offs o; int p = 0;
#define ALLOC(name, bytes) { p = (p + 15) & ~15; o.name = p; p += (bytes); }
  ALLOC(l1s, KIH*4) ALLOC(hs, HID*4)
  ALLOC(wih, res ? 30*KRES : 16) ALLOC(whh, res ? 30*KHH : 16)
  ALLOC(w2s, res ? 4*HID : 16)
  ALLOC(w3s, 16*48*4) ALLOC(cs, 240*4) ALLOC(as_, 64) ALLOC(b3s, 192*4)
  ALLOC(bih, 120) ALLOC(bhh, 120) ALLOC(b2s, 16)
  ALLOC(gis, 120) ALLOC(ghs, 120)
  ALLOC(ts, 64) ALLOC(inn, 192) ALLOC(kn, 256)
  ALLOC(dxs, 16) ALLOC(xpri, 16) ALLOC(xpo, 16) ALLOC(b4, 16) ALLOC(nrm, 16)
  ALLOC(l2r, 16) ALLOC(slp, 64)
#undef ALLOC
  o.total = (p + 63) & ~63;
  return o;
}

struct Params {
  const float *A, *C, *x0, *h0, *y, *W1, *b1, *Wih, *Whh, *bih, *bhh, *W2, *b2, *W3, *b3;
  const uint8_t *wih8, *w1e;
  uint64_t *hbp, *slt;
  float *out;
  int resident;
};

__device__ __forceinline__ uint8_t f2fp8(float v) {
  v = fminf(fmaxf(v * 128.f, -448.f), 448.f);
  int pk = __builtin_amdgcn_cvt_pk_fp8_f32(v, v, 0, false);
  return (uint8_t)(pk & 0xff);
}

// fire-and-forget tagged publish: one self-validating 8B word.
__device__ __forceinline__ void pub64(uint64_t* a, uint32_t tag, float v) {
  uint64_t w = ((uint64_t)tag << 32) | (uint64_t)__float_as_uint(v);
  __hip_atomic_store(a, w, __ATOMIC_RELAXED, __HIP_MEMORY_SCOPE_AGENT);
}

// full-packet poll: all N tagged words each round; hot for SPINHOT rounds,
// then s_sleep(2) throttle (deadlock-safety only).
template<int N>
__device__ __forceinline__ void poll_pkt(const uint64_t* base, uint32_t want,
                                         float* out, bool& dead) {
  uint64_t v[N];
  uint32_t spins = 0;
  for (;;) {
    bool ok = true;
#pragma unroll
    for (int k = 0; k < N; ++k)
      v[k] = __hip_atomic_load(base + k, __ATOMIC_RELAXED, __HIP_MEMORY_SCOPE_AGENT);
#pragma unroll
    for (int k = 0; k < N; ++k) ok &= ((uint32_t)(v[k] >> 32) == want);
    if (ok || dead) break;
    ++spins;
    if (spins > SPINHOT) __builtin_amdgcn_s_sleep(2);
    if (spins > SPINCAP) dead = true;
  }
#pragma unroll
  for (int k = 0; k < N; ++k) out[k] = __uint_as_float((uint32_t)v[k]);
}

// 16-wide fp8 dot fragment: acc += dot(fp8x16(w), [a0 a1 a2 a3])
__device__ __forceinline__ float fma16(uint4 w, float4 a0, float4 a1,
                                       float4 a2, float4 a3, float acc) {
  v2f l0 = __builtin_amdgcn_cvt_pk_f32_fp8((int)w.x, false);
  v2f h0 = __builtin_amdgcn_cvt_pk_f32_fp8((int)w.x, true);
  v2f l1 = __builtin_amdgcn_cvt_pk_f32_fp8((int)w.y, false);
  v2f h1 = __builtin_amdgcn_cvt_pk_f32_fp8((int)w.y, true);
  v2f l2 = __builtin_amdgcn_cvt_pk_f32_fp8((int)w.z, false);
  v2f h2 = __builtin_amdgcn_cvt_pk_f32_fp8((int)w.z, true);
  v2f l3 = __builtin_amdgcn_cvt_pk_f32_fp8((int)w.w, false);
  v2f h3 = __builtin_amdgcn_cvt_pk_f32_fp8((int)w.w, true);
  acc = fmaf(l0.x,a0.x,acc); acc = fmaf(l0.y,a0.y,acc);
  acc = fmaf(h0.x,a0.z,acc); acc = fmaf(h0.y,a0.w,acc);
  acc = fmaf(l1.x,a1.x,acc); acc = fmaf(l1.y,a1.y,acc);
  acc = fmaf(h1.x,a1.z,acc); acc = fmaf(h1.y,a1.w,acc);
  acc = fmaf(l2.x,a2.x,acc); acc = fmaf(l2.y,a2.y,acc);
  acc = fmaf(h2.x,a2.z,acc); acc = fmaf(h2.y,a2.w,acc);
  acc = fmaf(l3.x,a3.x,acc); acc = fmaf(l3.y,a3.y,acc);
  acc = fmaf(h3.x,a3.z,acc); acc = fmaf(h3.y,a3.w,acc);
  return acc;
}

// fp8 row-dot, LDS weights, <=4 rows/wave, lanes split K.
__device__ __forceinline__ void dot8_lds(
    const float* __restrict__ acts, const uint8_t* __restrict__ w, int stride,
    int K, const int* lrows, int nr, int lane, float acc[4])
{
  int kb = 0;
  for (; kb + 256 <= K; kb += 256) {
    const float4 a = ((const float4*)(acts + kb))[lane];
#pragma unroll
    for (int j = 0; j < 4; ++j) if (j < nr) {
      uint32_t wb = *(const uint32_t*)(w + (size_t)lrows[j]*stride + kb + (lane<<2));
      v2f lo = __builtin_amdgcn_cvt_pk_f32_fp8((int)wb, false);
      v2f hi = __builtin_amdgcn_cvt_pk_f32_fp8((int)wb, true);
      acc[j] = fmaf(lo.x, a.x, acc[j]); acc[j] = fmaf(lo.y, a.y, acc[j]);
      acc[j] = fmaf(hi.x, a.z, acc[j]); acc[j] = fmaf(hi.y, a.w, acc[j]);
    }
  }
  int rem = K - kb;
  if ((lane << 2) < rem) {
    const float4 a = ((const float4*)(acts + kb))[lane];
#pragma unroll
    for (int j = 0; j < 4; ++j) if (j < nr) {
      uint32_t wb = *(const uint32_t*)(w + (size_t)lrows[j]*stride + kb + (lane<<2));
      v2f lo = __builtin_amdgcn_cvt_pk_f32_fp8((int)wb, false);
      v2f hi = __builtin_amdgcn_cvt_pk_f32_fp8((int)wb, true);
      acc[j] = fmaf(lo.x, a.x, acc[j]); acc[j] = fmaf(lo.y, a.y, acc[j]);
      acc[j] = fmaf(hi.x, a.z, acc[j]); acc[j] = fmaf(hi.y, a.w, acc[j]);
    }
  }
}

// fp8 row-dot, global weights, cols [K0,K).
__device__ __forceinline__ void dot8_glb(
    const float* __restrict__ acts, const uint8_t* __restrict__ gw, int gstride,
    int K0, int K, const int* grows, int nr, int lane, float acc[4])
{
  int kb = K0;
  for (; kb + 512 <= K; kb += 512) {
    const float4 a0 = ((const float4*)(acts + kb))[lane*2];
    const float4 a1 = ((const float4*)(acts + kb))[lane*2 + 1];
#pragma unroll
    for (int j = 0; j < 4; ++j) if (j < nr) {
      uint2 wb = *(const uint2*)(gw + (size_t)grows[j]*gstride + kb + (lane<<3));
      v2f l0 = __builtin_amdgcn_cvt_pk_f32_fp8((int)wb.x, false);
      v2f h0 = __builtin_amdgcn_cvt_pk_f32_fp8((int)wb.x, true);
      v2f l1 = __builtin_amdgcn_cvt_pk_f32_fp8((int)wb.y, false);
      v2f h1 = __builtin_amdgcn_cvt_pk_f32_fp8((int)wb.y, true);
      acc[j] = fmaf(l0.x, a0.x, acc[j]); acc[j] = fmaf(l0.y, a0.y, acc[j]);
      acc[j] = fmaf(h0.x, a0.z, acc[j]); acc[j] = fmaf(h0.y, a0.w, acc[j]);
      acc[j] = fmaf(l1.x, a1.x, acc[j]); acc[j] = fmaf(l1.y, a1.y, acc[j]);
      acc[j] = fmaf(h1.x, a1.z, acc[j]); acc[j] = fmaf(h1.y, a1.w, acc[j]);
    }
  }
  for (int e = kb + lane; e < K; e += 64) {
    float a = acts[e];
#pragma unroll
    for (int j = 0; j < 4; ++j) if (j < nr) {
      v2f lo = __builtin_amdgcn_cvt_pk_f32_fp8(
          (int)(uint32_t)gw[(size_t)grows[j]*gstride + e], false);
      acc[j] = fmaf(lo.x, a, acc[j]);
    }
  }
}

// f32 row-dot, global weights (fallback ghh).
__device__ __forceinline__ void dotf_glb(
    const float* __restrict__ acts, const float* __restrict__ gw, int gstride,
    int K, const int* grows, int nr, int lane, float acc[4])
{
  for (int k = lane; k < K; k += 64) {
    float a = acts[k];
#pragma unroll
    for (int j = 0; j < 4; ++j) if (j < nr)
      acc[j] = fmaf(gw[(size_t)grows[j]*gstride + k], a, acc[j]);
  }
}

extern "C" __global__ void __launch_bounds__(NTHR, 2) knet_main(Params p)
{
  extern __shared__ char smem[];
  const Offs o = mkoffs(p.resident);
  float*   L1S  = (float*)(smem + o.l1s);
  float*   HS   = (float*)(smem + o.hs);
  uint8_t* WIHR = (uint8_t*)(smem + o.wih);
  uint8_t* WHHR = (uint8_t*)(smem + o.whh);
  uint8_t* W2S  = (uint8_t*)(smem + o.w2s);
  float*   W3S  = (float*)(smem + o.w3s);
  float*   CS   = (float*)(smem + o.cs);
  float*   AS   = (float*)(smem + o.as_);
  float*   B3S  = (float*)(smem + o.b3s);
  float*   BIH  = (float*)(smem + o.bih);
  float*   BHH  = (float*)(smem + o.bhh);
  float*   B2S  = (float*)(smem + o.b2s);
  float*   GIS  = (float*)(smem + o.gis);
  float*   GHS  = (float*)(smem + o.ghs);
  float*   TS   = (float*)(smem + o.ts);
  float*   INNS = (float*)(smem + o.inn);
  float*   KN   = (float*)(smem + o.kn);
  float*   DXS  = (float*)(smem + o.dxs);
  float*   XPRI = (float*)(smem + o.xpri);
  float*   XPO  = (float*)(smem + o.xpo);
  float*   B4   = (float*)(smem + o.b4);
  float*   NRM  = (float*)(smem + o.nrm);
  float*   L2R  = (float*)(smem + o.l2r);
  float*   SLP  = (float*)(smem + o.slp);

  const int tid  = (int)threadIdx.x;
  const int bid  = (int)blockIdx.x;
  const int lane = tid & 63;
  const int wv   = tid >> 6;
  const int rows2 = (bid < NL2B) ? 4 : 0;              // uniform l2 ownership
  const int r2s   = bid * 4;
  bool dead = false;

  int lrows[4] = {0,0,0,0}, grows[4] = {0,0,0,0};
  int nr = 0;
#pragma unroll
  for (int j = 0; j < 4; ++j) {
    int row = wv + 8*j;
    if (row < 30) { int u = row/3, g = row - 3*u;
      lrows[nr] = row; grows[nr] = g*HID + bid*UPB + u; ++nr; }
  }

  // ---------------- one-time staging ----------------
  for (int i = tid; i < rows2*192; i += NTHR) { int rl = i/192, rem = i - rl*192;
    W3S[i] = p.W3[(size_t)rem*768 + (r2s + rl)]; }
  for (int i = tid; i < 240; i += NTHR) CS[i] = p.C[i];
  if (tid < 16) AS[tid] = p.A[tid];
  for (int i = tid; i < 192; i += NTHR) B3S[i] = p.b3[i];
  if (tid < rows2) B2S[tid] = p.b2[r2s + tid];
  if (tid < 30) {
    int u = tid/3, g = tid - 3*u, ug = bid*UPB + u;
    BIH[tid] = p.bih[g*HID + ug];
    BHH[tid] = p.bhh[g*HID + ug];
  }
  for (int i = tid; i < HID; i += NTHR) HS[i] = p.h0[i];
  // own-unit hidden state held in a register (tid < UPB only).
  float myh = (tid < UPB) ? p.h0[(size_t)bid*UPB + tid] : 0.f;
  if (p.resident) {
    const int kd = KRES >> 2;                   // W_ih resident cols from fp8 ws
    uint32_t* W32 = (uint32_t*)WIHR;
    for (int i = tid; i < 30*kd; i += NTHR) {
      int row = i / kd, c = i - row*kd;
      int u = row/3, g = row - 3*u, gr = g*HID + bid*UPB + u;
      W32[i] = ((const uint32_t*)p.wih8)[(size_t)gr*(KIH/4) + c];
    }
    for (int i = tid; i < 30*KHH; i += NTHR) {  // W_hh rows f32->fp8
      int row = i / KHH, k = i - row*KHH;
      int u = row/3, g = row - 3*u, gr = g*HID + bid*UPB + u;
      WHHR[i] = f2fp8(p.Whh[(size_t)gr*KHH + k]);
    }
    for (int i = tid; i < rows2*HID; i += NTHR) { // W2 slice f32->fp8
      int rl = i / HID, k = i - rl*HID;
      W2S[i] = f2fp8(p.W2[(size_t)(r2s+rl)*HID + k]);
    }
  }
  // streamed W_ih cols [KRES,4160) hoisted into VGPRs (constant across steps)
  uint2 pf[4][5];
#pragma unroll
  for (int j = 0; j < 4; ++j)
#pragma unroll
    for (int i = 0; i < 5; ++i) pf[j][i] = make_uint2(0u, 0u);
#pragma unroll
  for (int j = 0; j < 4; ++j) if (j < nr)
#pragma unroll
    for (int i = 0; i < 5; ++i)
      pf[j][i] = *(const uint2*)(p.wih8 + (size_t)grows[j]*KIH + KRES + i*512 + (lane<<3));
  __syncthreads();

  // small chain producing step-`ycol` inputs: INNS, KN, B4, TS, full l1.
  auto small_chain = [&](int ycol) {
    if (tid < 48) {
      float s = CS[tid*5 + 4];
#pragma unroll
      for (int k = 0; k < 4; ++k) s += CS[tid*5 + k] * XPRI[k];
      INNS[tid] = p.y[(size_t)tid*TSEQ + ycol] - s;
    }
    __syncthreads();
    if (wv == 0) {                               // parallel ||inn||
      float q = (lane < 48) ? INNS[lane]*INNS[lane] : 0.f;
#pragma unroll
      for (int m = 32; m >= 1; m >>= 1) q += __shfl_xor(q, m, 64);
      if (lane == 0) NRM[0] = fmaxf(sqrtf(q), 1e-12f);
    } else if (wv == 1) {                        // parallel ||dx||
      float q = (lane < 4) ? DXS[lane]*DXS[lane] : 0.f;
#pragma unroll
      for (int m = 32; m >= 1; m >>= 1) q += __shfl_xor(q, m, 64);
      if (lane == 0) NRM[1] = fmaxf(sqrtf(q), 1e-12f);
    }
    __syncthreads();
    if (tid < 48) KN[tid] = INNS[tid] / NRM[0];
    else if (tid < 52) KN[tid] = DXS[tid-48] / NRM[1];
    else if (tid == 52) KN[tid] = 1.0f;
    else if (tid < 64) KN[tid] = 0.0f;
    else if (tid < 68) {
      int i = tid - 64; float s = 0;
      for (int j = 0; j < 48; ++j) s += B3S[i*48 + j] * INNS[j];
      B4[i] = s;
    }
    if (tid >= 128 && tid < 128 + rows2*4) {
      int idx = tid - 128, rl = idx >> 2, i = idx & 3;
      float s = 0;
      for (int j = 0; j < 48; ++j) s += W3S[rl*192 + i*48 + j] * INNS[j];
      TS[i*4 + rl] = s;
    }
    __syncthreads();
    {                                            // redundant full l1
      float4 kn[16];
#pragma unroll
      for (int c = 0; c < 16; ++c) kn[c] = ((const float4*)KN)[c];
      for (int r = tid; r < KIH; r += NTHR) {
        const uint4* wp = (const uint4*)(p.w1e + (size_t)r*64);
        float acc = 0.f;
#pragma unroll
        for (int q = 0; q < 4; ++q) {
          uint4 w = wp[q];
          acc = fma16(w, kn[q*4+0], kn[q*4+1], kn[q*4+2], kn[q*4+3], acc);
        }
        L1S[r] = fmaxf(acc * INVWS, 0.f);
      }
    }
    __syncthreads();
  };

  auto ghh = [&]() {                             // W_hh @ HS -> GHS
    float acc[4] = {0,0,0,0};
    if (p.resident) dot8_lds(HS, WHHR, KHH, KHH, lrows, nr, lane, acc);
    else            dotf_glb(HS, p.Whh, KHH, KHH, grows, nr, lane, acc);
#pragma unroll
    for (int m = 32; m >= 1; m >>= 1)
#pragma unroll
      for (int j = 0; j < 4; ++j) acc[j] += __shfl_xor(acc[j], m, 64);
    if (lane == 0)
#pragma unroll
      for (int j = 0; j < 4; ++j) if (j < nr) GHS[lrows[j]] = acc[j];
  };

  // ---------------- pre-loop ----------------
  if (tid < 4) { XPO[tid] = p.x0[tid]; DXS[tid] = 0.f; }
  __syncthreads();
  if (tid < 4) {
    float s = 0;
#pragma unroll
    for (int j = 0; j < 4; ++j) s += AS[tid*4 + j] * XPO[j];
    XPRI[tid] = s;
  }
  __syncthreads();
  small_chain(0);
  ghh();
  __syncthreads();

  // ---------------- main sequence ----------------
  for (int t = 0; t < TSEQ; ++t) {
    const int par = t & 1;
    const uint32_t want = (uint32_t)(t + 1);

    // ---- A: gate-dot gi = W_ih @ l1(t) ----
    {
      float acc[4] = {0,0,0,0};
      if (p.resident) dot8_lds(L1S, WIHR, KRES, KRES, lrows, nr, lane, acc);
      else            dot8_glb(L1S, p.wih8, KIH, 0, KRES, grows, nr, lane, acc);
#pragma unroll
      for (int i = 0; i < 5; ++i) {              // VGPR-held streamed cols
        const float4 a0 = ((const float4*)(L1S + KRES + i*512))[lane*2];
        const float4 a1 = ((const float4*)(L1S + KRES + i*512))[lane*2 + 1];
#pragma unroll
        for (int j = 0; j < 4; ++j) if (j < nr) {
          uint2 w = pf[j][i];
          v2f l0 = __builtin_amdgcn_cvt_pk_f32_fp8((int)w.x, false);
          v2f h0 = __builtin_amdgcn_cvt_pk_f32_fp8((int)w.x, true);
          v2f l1v = __builtin_amdgcn_cvt_pk_f32_fp8((int)w.y, false);
          v2f h1 = __builtin_amdgcn_cvt_pk_f32_fp8((int)w.y, true);
          acc[j] = fmaf(l0.x, a0.x, acc[j]); acc[j] = fmaf(l0.y, a0.y, acc[j]);
          acc[j] = fmaf(h0.x, a0.z, acc[j]); acc[j] = fmaf(h0.y, a0.w, acc[j]);
          acc[j] = fmaf(l1v.x, a1.x, acc[j]); acc[j] = fmaf(l1v.y, a1.y, acc[j]);
          acc[j] = fmaf(h1.x, a1.z, acc[j]); acc[j] = fmaf(h1.y, a1.w, acc[j]);
        }
      }
#pragma unroll
      for (int m = 32; m >= 1; m >>= 1)
#pragma unroll
        for (int j = 0; j < 4; ++j) acc[j] += __shfl_xor(acc[j], m, 64);
      if (lane == 0)
#pragma unroll
        for (int j = 0; j < 4; ++j) if (j < nr) GIS[lrows[j]] = acc[j];
    }
    __syncthreads();

    // ---- B: h(t) + fire-and-forget tagged publish (tid 0..9) ----
    if (tid < UPB) {
      int r0 = tid*3;
      float gi0 = GIS[r0+0]*INVWS + BIH[r0+0], gh0 = GHS[r0+0]*INVWS + BHH[r0+0];
      float gi1 = GIS[r0+1]*INVWS + BIH[r0+1], gh1 = GHS[r0+1]*INVWS + BHH[r0+1];
      float gi2 = GIS[r0+2]*INVWS + BIH[r0+2], gh2 = GHS[r0+2]*INVWS + BHH[r0+2];
      float rg = 1.f/(1.f + expf(-(gi0+gh0)));
      float zg = 1.f/(1.f + expf(-(gi1+gh1)));
      float ng = tanhf(gi2 + rg*gh2);
      float hnew = (1.f - zg)*ng + zg*myh;
      myh = hnew;
      pub64(p.hbp + (((size_t)par*NBLK + bid) << 4) + tid, want, hnew);
    }
    __syncthreads();   // PACING barrier (R8): no wave enters the C-poll
                       // before this block's publish has been issued.

    // ---- C: h broadcast consume -> HS (waves 0-3) ----
    if (wv < 4) {
      int idx = (wv << 6) | lane;
      if (idx < NBLK) {
        float v[10];
        poll_pkt<10>(p.hbp + (((size_t)par*NBLK + idx) << 4), want, v, dead);
#pragma unroll
        for (int k = 0; k < 10; ++k) HS[idx*10 + k] = v[k];
      }
    }
    __syncthreads();

    // ---- D: l2 rows, one per wave on waves 4-7 (blocks < NL2B) ----
    if (rows2 && wv >= 4) {
      const int rl = wv - 4;
      float a2 = 0.f;
      if (p.resident) {
        int kb = 0;
        for (; kb + 256 <= HID; kb += 256) {
          const float4 a = ((const float4*)(HS + kb))[lane];
          uint32_t wb = *(const uint32_t*)(W2S + rl*HID + kb + (lane<<2));
          v2f lo = __builtin_amdgcn_cvt_pk_f32_fp8((int)wb, false);
          v2f hi = __builtin_amdgcn_cvt_pk_f32_fp8((int)wb, true);
          a2 = fmaf(lo.x, a.x, a2); a2 = fmaf(lo.y, a.y, a2);
          a2 = fmaf(hi.x, a.z, a2); a2 = fmaf(hi.y, a.w, a2);
        }
        if ((lane << 2) < HID - kb) {
          const float4 a = ((const float4*)(HS + kb))[lane];
          uint32_t wb = *(const uint32_t*)(W2S + rl*HID + kb + (lane<<2));
          v2f lo = __builtin_amdgcn_cvt_pk_f32_fp8((int)wb, false);
          v2f hi = __builtin_amdgcn_cvt_pk_f32_fp8((int)wb, true);
          a2 = fmaf(lo.x, a.x, a2); a2 = fmaf(lo.y, a.y, a2);
          a2 = fmaf(hi.x, a.z, a2); a2 = fmaf(hi.y, a.w, a2);
        }
        a2 *= INVWS;
      } else {
        for (int k = lane; k < HID; k += 64)
          a2 = fmaf(p.W2[(size_t)(r2s+rl)*HID + k], HS[k], a2);
      }
#pragma unroll
      for (int m = 32; m >= 1; m >>= 1) a2 += __shfl_xor(a2, m, 64);
      if (lane == 0) L2R[rl] = fmaxf(a2 + B2S[rl], 0.f);
    }
    __syncthreads();
    if (rows2 && tid < 4) {                      // publish 4 slot words
      float cp = L2R[0]*TS[tid*4+0] + L2R[1]*TS[tid*4+1]
               + L2R[2]*TS[tid*4+2] + L2R[3]*TS[tid*4+3];
      pub64(p.slt + (((size_t)par*NBLK + bid) << 3) + tid, want, cp);
    }

    // ---- E: ghh(t) for step t+1 (all waves; covers slot flight) ----
    ghh();

    // ---- F: slot reduce (waves 0-2: 192 packets) ----
    if (wv < 3) {
      int idx = (wv << 6) | lane;
      float v[4];
      poll_pkt<4>(p.slt + (((size_t)par*NBLK + idx) << 3), want, v, dead);
      float s0 = v[0], s1 = v[1], s2 = v[2], s3 = v[3];
#pragma unroll
      for (int m = 32; m >= 1; m >>= 1) {
        s0 += __shfl_xor(s0, m, 64); s1 += __shfl_xor(s1, m, 64);
        s2 += __shfl_xor(s2, m, 64); s3 += __shfl_xor(s3, m, 64);
      }
      if (lane == 0) {
        SLP[wv*4+0] = s0; SLP[wv*4+1] = s1; SLP[wv*4+2] = s2; SLP[wv*4+3] = s3;
      }
    }
    __syncthreads();

    // ---- G: posterior + next-step chain ----
    if (tid < 4) {
      float c = SLP[tid] + SLP[4 + tid] + SLP[8 + tid];
      float xp = XPRI[tid] + (c + B4[tid]) * 1e-4f;
      XPO[tid] = xp;
      if (bid == 0) p.out[(size_t)tid*TSEQ + t] = xp;
    }
    __syncthreads();
    if (t + 1 < TSEQ) {
      if (tid < 4) {
        float xo = XPO[tid];
        DXS[tid] = xo - XPRI[tid];
        float s = 0;
#pragma unroll
        for (int j = 0; j < 4; ++j) s += AS[tid*4 + j] * XPO[j];
        XPRI[tid] = s;
      }
      __syncthreads();
      small_chain(t + 1);                        // ends with syncthreads
    }
  }
}

// f32 -> fp8 e4m3 (x128), 4 elements per thread (W_ih full).
extern "C" __global__ void knet_cvt_fp8(const float* __restrict__ src,
                                        uint8_t* __restrict__ dst, long n4) {
  long stride = (long)gridDim.x * blockDim.x;
  for (long i = (long)blockIdx.x*blockDim.x + threadIdx.x; i < n4; i += stride) {
    float4 v = ((const float4*)src)[i];
    float a0 = fminf(fmaxf(v.x * 128.f, -448.f), 448.f);
    float a1 = fminf(fmaxf(v.y * 128.f, -448.f), 448.f);
    float a2 = fminf(fmaxf(v.z * 128.f, -448.f), 448.f);
    float a3 = fminf(fmaxf(v.w * 128.f, -448.f), 448.f);
    int pk = __builtin_amdgcn_cvt_pk_fp8_f32(a0, a1, 0, false);
    pk = __builtin_amdgcn_cvt_pk_fp8_f32(a2, a3, pk, true);
    ((uint32_t*)dst)[i] = (uint32_t)pk;
  }
}

// Build W1ext fp8: row r = [W1[r,0:52], b1[r], 0 x11] * 128, 64 B/row.
extern "C" __global__ void knet_build_w1e(const float* __restrict__ W1,
                                          const float* __restrict__ b1,
                                          uint8_t* __restrict__ dst) {
  int r = blockIdx.x * blockDim.x + threadIdx.x;
  if (r >= KIH) return;
  float v[64];
#pragma unroll 13
  for (int q = 0; q < 13; ++q) {
    float4 w = ((const float4*)(W1 + (size_t)r*52))[q];
    v[q*4+0] = w.x; v[q*4+1] = w.y; v[q*4+2] = w.z; v[q*4+3] = w.w;
  }
  v[52] = b1[r];
  for (int i = 53; i < 64; ++i) v[i] = 0.f;
  uint32_t out[16];
#pragma unroll 16
  for (int d = 0; d < 16; ++d) {
    float a0 = fminf(fmaxf(v[d*4+0] * 128.f, -448.f), 448.f);
    float a1 = fminf(fmaxf(v[d*4+1] * 128.f, -448.f), 448.f);
    float a2 = fminf(fmaxf(v[d*4+2] * 128.f, -448.f), 448.f);
    float a3 = fminf(fmaxf(v[d*4+3] * 128.f, -448.f), 448.f);
    int pk = __builtin_amdgcn_cvt_pk_fp8_f32(a0, a1, 0, false);
    pk = __builtin_amdgcn_cvt_pk_fp8_f32(a2, a3, pk, true);
    out[d] = (uint32_t)pk;
  }
  uint4* dp = (uint4*)(dst + (size_t)r*64);
#pragma unroll 4
  for (int q = 0; q < 4; ++q)
    dp[q] = make_uint4(out[q*4+0], out[q*4+1], out[q*4+2], out[q*4+3]);
}

extern "C" void kernel_launch(void* const* d_in, const int* in_sizes, int n_in,
                              void* d_out, int out_size, void* d_ws, size_t ws_size,
                              hipStream_t stream)
{
  if (ws_size < (size_t)WS_END) return;   // 29.3 MB (proven available)
  uint8_t* ws = (uint8_t*)d_ws;

  knet_cvt_fp8<<<2048, 256, 0, stream>>>((const float*)d_in[7], ws + WS_WIH8,
                                         (long)G3*KIH/4);
  knet_build_w1e<<<(KIH + 255)/256, 256, 0, stream>>>(
      (const float*)d_in[5], (const float*)d_in[6], ws + WS_W1E);
  // no memset needed: word tags are exact-match (t+1); 0xAA poison never matches

  int resident = 1;
  Offs o = mkoffs(resident);
  hipError_t e = hipFuncSetAttribute((const void*)knet_main,
                                     hipFuncAttributeMaxDynamicSharedMemorySize,
                                     o.total);
  if (e != hipSuccess) {
    resident = 0; o = mkoffs(resident);
    (void)hipFuncSetAttribute((const void*)knet_main,
                              hipFuncAttributeMaxDynamicSharedMemorySize, o.total);
  }

  Params p;
  p.A   = (const float*)d_in[0];  p.C   = (const float*)d_in[1];
  p.x0  = (const float*)d_in[2];  p.h0  = (const float*)d_in[3];
  p.y   = (const float*)d_in[4];
  p.W1  = (const float*)d_in[5];  p.b1  = (const float*)d_in[6];
  p.Wih = (const float*)d_in[7];  p.Whh = (const float*)d_in[8];
  p.bih = (const float*)d_in[9];  p.bhh = (const float*)d_in[10];
  p.W2  = (const float*)d_in[11]; p.b2  = (const float*)d_in[12];
  p.W3  = (const float*)d_in[13]; p.b3  = (const float*)d_in[14];
  p.wih8 = ws + WS_WIH8;
  p.w1e  = ws + WS_W1E;
  p.hbp  = (uint64_t*)(ws + WS_HBP);
  p.slt  = (uint64_t*)(ws + WS_SLT);
  p.out  = (float*)d_out;
  p.resident = resident;

  knet_main<<<NBLK, NTHR, (size_t)o.total, stream>>>(p);
}